// Round 1
// baseline (2269.865 us; speedup 1.0000x reference)
//
#include <hip/hip_runtime.h>

#define NN 10000
#define NE 160000
#define INV_SQRT3f 0.57735026918962576f
#define INV_SQRT2f 0.70710678118654752f

__device__ __forceinline__ float sigm(float x){ return 1.f/(1.f+__expf(-x)); }
__device__ __forceinline__ float siluf(float x){ return x*sigm(x); }
__device__ __forceinline__ float sleaky(float x){ return 0.6f*x + 0.4f*x*(2.f*sigm(x)-1.f); }
__device__ __forceinline__ void atomicMaxF(float* a, float v){
  v += 0.0f;  // canonicalize -0.0 -> +0.0 so the int trick is safe
  if (v >= 0.f) atomicMax((int*)a, __float_as_int(v));
  else          atomicMin((unsigned int*)a, __float_as_uint(v));
}

// ---------------------------------------------------------------- init
__global__ __launch_bounds__(256) void k_init(float* __restrict__ num,
                                              float* __restrict__ den,
                                              int* __restrict__ mx) {
  int i = blockIdx.x*256 + threadIdx.x;
  if (i < NN*320) num[i] = 0.f;
  if (i < NN*8) { den[i] = 0.f; mx[i] = 0xFF800000; } // -inf bits
}

// ---------------------------------------------------------------- node pre
// ms_s = s@Wsrc_s + bsrc ; md_s = s@Wdst_s ; ms_v/md_v = v einsum W*_v
// 8 nodes per 256-thread block. LDS layout [feature][node] for float4 GEMV reads.
__global__ __launch_bounds__(256) void node_pre(
    const float* __restrict__ x,
    const float* __restrict__ Wsrc_s, const float* __restrict__ Wsrc_v,
    const float* __restrict__ bsrc,
    const float* __restrict__ Wdst_s, const float* __restrict__ Wdst_v,
    float* __restrict__ ms_s, float* __restrict__ md_s,
    float* __restrict__ ms_v, float* __restrict__ md_v) {
  __shared__ __align__(16) float s_s[128*8];
  __shared__ __align__(16) float s_v[192*8];
  const int tid = threadIdx.x;
  const int n0 = blockIdx.x*8;
  for (int idx = tid; idx < 8*320; idx += 256) {
    int n = idx/320, d = idx - n*320;
    float val = x[(n0+n)*320 + d];
    if (d < 128) s_s[d*8+n] = val;
    else         s_v[(d-128)*8+n] = val;   // (d-128) == m*3+c
  }
  __syncthreads();
  { // scalar part: thread = out col j, g-split nodes (4 each)
    int g = tid>>7, j = tid&127;
    float accs[4], accd[4];
    float b = bsrc[j];
    #pragma unroll
    for (int i=0;i<4;i++){ accs[i]=b; accd[i]=0.f; }
    for (int k=0;k<128;k++) {
      float w1 = Wsrc_s[k*128+j], w2 = Wdst_s[k*128+j];
      float4 sv = *(const float4*)&s_s[k*8+g*4];
      accs[0]+=sv.x*w1; accs[1]+=sv.y*w1; accs[2]+=sv.z*w1; accs[3]+=sv.w*w1;
      accd[0]+=sv.x*w2; accd[1]+=sv.y*w2; accd[2]+=sv.z*w2; accd[3]+=sv.w*w2;
    }
    #pragma unroll
    for (int i=0;i<4;i++){ int n=n0+g*4+i; ms_s[n*128+j]=accs[i]; md_s[n*128+j]=accd[i]; }
  }
  if (tid < 192) { // vector part: thread = (c,k)
    int c = tid>>6, k = tid&63;
    float accs[8], accd[8];
    #pragma unroll
    for (int e=0;e<8;e++){ accs[e]=0.f; accd[e]=0.f; }
    for (int m=0;m<64;m++) {
      float w1 = Wsrc_v[m*64+k], w2 = Wdst_v[m*64+k];
      float4 v0 = *(const float4*)&s_v[(m*3+c)*8];
      float4 v1 = *(const float4*)&s_v[(m*3+c)*8+4];
      accs[0]+=v0.x*w1; accs[1]+=v0.y*w1; accs[2]+=v0.z*w1; accs[3]+=v0.w*w1;
      accs[4]+=v1.x*w1; accs[5]+=v1.y*w1; accs[6]+=v1.z*w1; accs[7]+=v1.w*w1;
      accd[0]+=v0.x*w2; accd[1]+=v0.y*w2; accd[2]+=v0.z*w2; accd[3]+=v0.w*w2;
      accd[4]+=v1.x*w2; accd[5]+=v1.y*w2; accd[6]+=v1.z*w2; accd[7]+=v1.w*w2;
    }
    #pragma unroll
    for (int e=0;e<8;e++){ int n=n0+e; ms_v[n*192+k*3+c]=accs[e]; md_v[n*192+k*3+c]=accd[e]; }
  }
}

// ---------------------------------------------------------------- edge pass 1: logits
// Only needs w1 (cols 0..127) and w4 (cols 320..383) of the radial output.
__global__ __launch_bounds__(256) void e1_logits(
    const float* __restrict__ ms_s, const float* __restrict__ md_s,
    const float* __restrict__ ms_v, const float* __restrict__ md_v,
    const int* __restrict__ esrc, const int* __restrict__ edst,
    const float* __restrict__ eattr, const float* __restrict__ escal,
    const float* __restrict__ rad_W1, const float* __restrict__ rad_b1,
    const float* __restrict__ rad_W2, const float* __restrict__ rad_off,
    const float* __restrict__ Walpha, const float* __restrict__ balpha,
    const float* __restrict__ alpha_dot,
    float* __restrict__ logits) {
  __shared__ __align__(16) float sm[7456];
  __shared__ int s_src[8], s_dst[8];
  float* s_es   = sm;          // 256
  float* s_h    = sm + 256;    // 512
  float* s_w    = sm + 768;    // 1536 (compact: [0..128)=w1, [128..192)=w4)
  float* s_msgs = sm + 2304;   // 1024
  float* s_msgv = sm + 3328;   // 1536
  float* s_ds   = sm + 4864;   // 1536
  float* s_p    = sm + 6400;   // 1024
  float* s_e0   = sm + 7424;   // 8
  float* s_e1   = sm + 7432;   // 24
  const int tid = threadIdx.x;
  const int eb = blockIdx.x*8;

  if (tid < 8) { s_src[tid] = esrc[eb+tid]; s_dst[tid] = edst[eb+tid]; }
  if (tid >= 32 && tid < 64) {
    int t = tid-32, e = t>>2, q = t&3;
    float a = eattr[(eb+e)*4+q];
    if (q == 0) s_e0[e] = a; else s_e1[(q-1)*8+e] = a;
  }
  { int e = tid>>5, i = tid&31; s_es[i*8+e] = escal[(eb+e)*32+i]; }
  __syncthreads();

  #pragma unroll
  for (int rep = 0; rep < 2; ++rep) {   // H = silu(es @ W1 + b1)
    int idx = tid + rep*256;
    int j = idx & 63, e = idx >> 6;
    float acc = rad_b1[j];
    #pragma unroll
    for (int i = 0; i < 32; ++i) acc += s_es[i*8+e]*rad_W1[i*64+j];
    s_h[j*8+e] = siluf(acc);
  }
  __syncthreads();

  if (tid < 192) {                      // w (192 needed cols)
    int j = tid < 128 ? tid : tid + 192;
    float acc[8]; float o = rad_off[j];
    #pragma unroll
    for (int e=0;e<8;e++) acc[e]=o;
    for (int k=0;k<64;k++) {
      float wv = rad_W2[k*448+j];
      float4 h0 = *(const float4*)&s_h[k*8];
      float4 h1 = *(const float4*)&s_h[k*8+4];
      acc[0]+=h0.x*wv; acc[1]+=h0.y*wv; acc[2]+=h0.z*wv; acc[3]+=h0.w*wv;
      acc[4]+=h1.x*wv; acc[5]+=h1.y*wv; acc[6]+=h1.z*wv; acc[7]+=h1.w*wv;
    }
    #pragma unroll
    for (int e=0;e<8;e++) s_w[tid*8+e] = acc[e];
  }
  for (int idx = tid; idx < 1024; idx += 256) {  // msg_s gather
    int e = idx>>7, m = idx&127;
    s_msgs[m*8+e] = ms_s[s_src[e]*128+m] + md_s[s_dst[e]*128+m];
  }
  for (int idx = tid; idx < 1536; idx += 256) {  // msg_v gather
    int e = idx/192, r = idx - e*192;
    s_msgv[r*8+e] = ms_v[s_src[e]*192+r] + md_v[s_dst[e]*192+r];
  }
  __syncthreads();

  for (int idx = tid; idx < 1024; idx += 256) {  // os1
    int e = idx>>7, m = idx&127;
    s_ds[m*8+e] = s_w[m*8+e]*s_msgs[m*8+e]*s_e0[e];
  }
  for (int idx = tid; idx < 512; idx += 256) {   // os2
    int e = idx>>6, k = idx&63;
    float d = s_msgv[(k*3+0)*8+e]*s_e1[0+e]
            + s_msgv[(k*3+1)*8+e]*s_e1[8+e]
            + s_msgv[(k*3+2)*8+e]*s_e1[16+e];
    s_ds[(128+k)*8+e] = s_w[(128+k)*8+e]*d*INV_SQRT3f;
  }
  __syncthreads();

  {                                              // al -> partial logits
    int g = tid>>7, j = tid&127;
    float acc[4]; float b = balpha[j];
    #pragma unroll
    for (int i=0;i<4;i++) acc[i]=b;
    for (int k=0;k<192;k++) {
      float wv = Walpha[k*128+j];
      float4 d4 = *(const float4*)&s_ds[k*8+g*4];
      acc[0]+=d4.x*wv; acc[1]+=d4.y*wv; acc[2]+=d4.z*wv; acc[3]+=d4.w*wv;
    }
    float ad = alpha_dot[j];
    #pragma unroll
    for (int i=0;i<4;i++) s_p[j*8+g*4+i] = sleaky(acc[i])*ad;
  }
  __syncthreads();

  if (tid < 64) {
    int e = tid>>3, h = tid&7;
    float s = 0.f;
    #pragma unroll
    for (int q=0;q<16;q++) s += s_p[(h*16+q)*8+e];
    logits[(eb+e)*8+h] = s;
  }
}

// ---------------------------------------------------------------- segment max
__global__ __launch_bounds__(256) void e_max(const float* __restrict__ logits,
                                             const int* __restrict__ edst,
                                             float* __restrict__ mx) {
  int i = blockIdx.x*256 + threadIdx.x;
  if (i < NE*8) {
    int e = i>>3, h = i&7;
    atomicMaxF(&mx[edst[e]*8+h], logits[i]);
  }
}

// ---------------------------------------------------------------- edge pass 2: value + aggregate
__global__ __launch_bounds__(256) void e2_agg(
    const float* __restrict__ ms_s, const float* __restrict__ md_s,
    const float* __restrict__ ms_v, const float* __restrict__ md_v,
    const int* __restrict__ esrc, const int* __restrict__ edst,
    const float* __restrict__ eattr, const float* __restrict__ escal,
    const float* __restrict__ rad_W1, const float* __restrict__ rad_b1,
    const float* __restrict__ rad_W2, const float* __restrict__ rad_off,
    const float* __restrict__ Wact_s, const float* __restrict__ bact,
    const float* __restrict__ Wact_v, const float* __restrict__ w_int,
    const float* __restrict__ Wval_s, const float* __restrict__ bval,
    const float* __restrict__ Wval_v,
    const float* __restrict__ logits, const float* __restrict__ mx,
    float* __restrict__ den, float* __restrict__ num) {
  __shared__ __align__(16) float sm[14624];
  __shared__ int s_src[8], s_dst[8];
  // region map (floats). Reuse after the producer phase is synced:
  float* s_w    = sm;            // 3584 ; later: s_scal (1536) + s_gated (1536)
  float* s_msgs = sm + 3584;     // 1024 ; later: s_out (2560 = msgs+msgv)
  float* s_msgv = sm + 4608;     // 1536
  float* s_ds   = sm + 6144;     // 1536 ; later: s_vs
  float* s_dv   = sm + 7680;     // 6144 ; later: s_vv
  float* s_es   = sm + 13824;    // 256  ; later: s_ex (64)
  float* s_h    = sm + 14080;    // 512
  float* s_e0   = sm + 14592;    // 8
  float* s_e1   = sm + 14600;    // 24
  float* s_scal = sm;
  float* s_gated= sm + 1536;
  float* s_out  = sm + 3584;
  float* s_vs   = sm + 6144;
  float* s_vv   = sm + 7680;
  float* s_ex   = sm + 13824;
  const int tid = threadIdx.x;
  const int eb = blockIdx.x*8;

  // P0: indices, attr, scalars
  if (tid < 8) { s_src[tid] = esrc[eb+tid]; s_dst[tid] = edst[eb+tid]; }
  if (tid >= 32 && tid < 64) {
    int t = tid-32, e = t>>2, q = t&3;
    float a = eattr[(eb+e)*4+q];
    if (q == 0) s_e0[e] = a; else s_e1[(q-1)*8+e] = a;
  }
  { int e = tid>>5, i = tid&31; s_es[i*8+e] = escal[(eb+e)*32+i]; }
  __syncthreads();

  // P1: H
  #pragma unroll
  for (int rep = 0; rep < 2; ++rep) {
    int idx = tid + rep*256;
    int j = idx & 63, e = idx >> 6;
    float acc = rad_b1[j];
    #pragma unroll
    for (int i = 0; i < 32; ++i) acc += s_es[i*8+e]*rad_W1[i*64+j];
    s_h[j*8+e] = siluf(acc);
  }
  __syncthreads();

  // P2: full w (448 cols) + msg gather
  for (int j = tid; j < 448; j += 256) {
    float acc[8]; float o = rad_off[j];
    #pragma unroll
    for (int e=0;e<8;e++) acc[e]=o;
    for (int k=0;k<64;k++) {
      float wv = rad_W2[k*448+j];
      float4 h0 = *(const float4*)&s_h[k*8];
      float4 h1 = *(const float4*)&s_h[k*8+4];
      acc[0]+=h0.x*wv; acc[1]+=h0.y*wv; acc[2]+=h0.z*wv; acc[3]+=h0.w*wv;
      acc[4]+=h1.x*wv; acc[5]+=h1.y*wv; acc[6]+=h1.z*wv; acc[7]+=h1.w*wv;
    }
    #pragma unroll
    for (int e=0;e<8;e++) s_w[j*8+e] = acc[e];
  }
  for (int idx = tid; idx < 1024; idx += 256) {
    int e = idx>>7, m = idx&127;
    s_msgs[m*8+e] = ms_s[s_src[e]*128+m] + md_s[s_dst[e]*128+m];
  }
  for (int idx = tid; idx < 1536; idx += 256) {
    int e = idx/192, r = idx - e*192;
    s_msgv[r*8+e] = ms_v[s_src[e]*192+r] + md_v[s_dst[e]*192+r];
  }
  __syncthreads();

  // P3: dtp1 -> ds, dv
  for (int idx = tid; idx < 1024; idx += 256) {       // os1
    int e = idx>>7, m = idx&127;
    s_ds[m*8+e] = s_w[m*8+e]*s_msgs[m*8+e]*s_e0[e];
  }
  for (int idx = tid; idx < 512; idx += 256) {        // os2 + ov2 + ov3
    int e = idx>>6, k = idx&63;
    float vx = s_msgv[(k*3+0)*8+e], vy = s_msgv[(k*3+1)*8+e], vz = s_msgv[(k*3+2)*8+e];
    float ex1 = s_e1[0+e], ey1 = s_e1[8+e], ez1 = s_e1[16+e];
    float d = vx*ex1 + vy*ey1 + vz*ez1;
    s_ds[(128+k)*8+e] = s_w[(320+k)*8+e]*d*INV_SQRT3f;
    float w3v = s_w[(256+k)*8+e]*s_e0[e];
    s_dv[((128+k)*3+0)*8+e] = w3v*vx;
    s_dv[((128+k)*3+1)*8+e] = w3v*vy;
    s_dv[((128+k)*3+2)*8+e] = w3v*vz;
    float w5 = s_w[(384+k)*8+e]*INV_SQRT2f;
    s_dv[((192+k)*3+0)*8+e] = w5*(vy*ez1 - vz*ey1);
    s_dv[((192+k)*3+1)*8+e] = w5*(vz*ex1 - vx*ez1);
    s_dv[((192+k)*3+2)*8+e] = w5*(vx*ey1 - vy*ex1);
  }
  for (int idx = tid; idx < 3072; idx += 256) {       // ov1
    int e = idx&7, r = idx>>3;   // r = m*3+c, m<128
    int m = r/3, c = r - m*3;
    s_dv[r*8+e] = s_w[(128+m)*8+e]*s_msgs[m*8+e]*s_e1[c*8+e];
  }
  __syncthreads();

  // P4: scal = ds@Wact_s + bact ; gated = dv . Wact_v   (w region now dead -> reuse)
  if (tid < 192) {
    {
      float acc[8]; float b = bact[tid];
      #pragma unroll
      for (int e=0;e<8;e++) acc[e]=b;
      for (int k=0;k<192;k++) {
        float wv = Wact_s[k*192+tid];
        float4 d0 = *(const float4*)&s_ds[k*8];
        float4 d1 = *(const float4*)&s_ds[k*8+4];
        acc[0]+=d0.x*wv; acc[1]+=d0.y*wv; acc[2]+=d0.z*wv; acc[3]+=d0.w*wv;
        acc[4]+=d1.x*wv; acc[5]+=d1.y*wv; acc[6]+=d1.z*wv; acc[7]+=d1.w*wv;
      }
      #pragma unroll
      for (int e=0;e<8;e++) s_scal[tid*8+e] = acc[e];
    }
    {
      int c = tid>>6, k = tid&63;
      float acc[8];
      #pragma unroll
      for (int e=0;e<8;e++) acc[e]=0.f;
      for (int m=0;m<256;m++) {
        float wv = Wact_v[m*64+k];
        float4 d0 = *(const float4*)&s_dv[(m*3+c)*8];
        float4 d1 = *(const float4*)&s_dv[(m*3+c)*8+4];
        acc[0]+=d0.x*wv; acc[1]+=d0.y*wv; acc[2]+=d0.z*wv; acc[3]+=d0.w*wv;
        acc[4]+=d1.x*wv; acc[5]+=d1.y*wv; acc[6]+=d1.z*wv; acc[7]+=d1.w*wv;
      }
      #pragma unroll
      for (int e=0;e<8;e++) s_gated[(k*3+c)*8+e] = acc[e];
    }
  }
  __syncthreads();

  // P5: activations + dtp2 -> vs (over ds), vv (over dv)
  for (int idx = tid; idx < 1024; idx += 256) {
    int e = idx>>7, m = idx&127;
    float v = siluf(s_scal[m*8+e]);
    s_vs[m*8+e] = w_int[m]*v*s_e0[e];
    float t = w_int[128+m]*v;
    s_vv[(m*3+0)*8+e] = t*s_e1[0+e];
    s_vv[(m*3+1)*8+e] = t*s_e1[8+e];
    s_vv[(m*3+2)*8+e] = t*s_e1[16+e];
  }
  for (int idx = tid; idx < 512; idx += 256) {
    int e = idx>>6, k = idx&63;
    float sg = sigm(s_scal[(128+k)*8+e]);
    float v0 = s_gated[(k*3+0)*8+e]*sg;
    float v1 = s_gated[(k*3+1)*8+e]*sg;
    float v2 = s_gated[(k*3+2)*8+e]*sg;
    float ex1 = s_e1[0+e], ey1 = s_e1[8+e], ez1 = s_e1[16+e];
    float d = v0*ex1 + v1*ey1 + v2*ez1;
    s_vs[(128+k)*8+e] = w_int[320+k]*d*INV_SQRT3f;
    float w3v = w_int[256+k]*s_e0[e];
    s_vv[((128+k)*3+0)*8+e] = w3v*v0;
    s_vv[((128+k)*3+1)*8+e] = w3v*v1;
    s_vv[((128+k)*3+2)*8+e] = w3v*v2;
    float w5 = w_int[384+k]*INV_SQRT2f;
    s_vv[((192+k)*3+0)*8+e] = w5*(v1*ez1 - v2*ey1);
    s_vv[((192+k)*3+1)*8+e] = w5*(v2*ex1 - v0*ez1);
    s_vv[((192+k)*3+2)*8+e] = w5*(v0*ey1 - v1*ex1);
  }
  __syncthreads();

  // P6: out_s, out_v into value layout; ex + den atomics
  {
    int g = tid>>7, j = tid&127;
    float acc[4]; float b = bval[j];
    #pragma unroll
    for (int i=0;i<4;i++) acc[i]=b;
    for (int k=0;k<192;k++) {
      float wv = Wval_s[k*128+j];
      float4 d4 = *(const float4*)&s_vs[k*8+g*4];
      acc[0]+=d4.x*wv; acc[1]+=d4.y*wv; acc[2]+=d4.z*wv; acc[3]+=d4.w*wv;
    }
    int h = j>>4, jj = j&15;
    #pragma unroll
    for (int i=0;i<4;i++) s_out[(g*4+i)*320 + h*40 + jj] = acc[i];
  }
  if (tid < 192) {
    int c = tid>>6, k = tid&63;
    float acc[8];
    #pragma unroll
    for (int e=0;e<8;e++) acc[e]=0.f;
    for (int m=0;m<256;m++) {
      float wv = Wval_v[m*64+k];
      float4 d0 = *(const float4*)&s_vv[(m*3+c)*8];
      float4 d1 = *(const float4*)&s_vv[(m*3+c)*8+4];
      acc[0]+=d0.x*wv; acc[1]+=d0.y*wv; acc[2]+=d0.z*wv; acc[3]+=d0.w*wv;
      acc[4]+=d1.x*wv; acc[5]+=d1.y*wv; acc[6]+=d1.z*wv; acc[7]+=d1.w*wv;
    }
    int h = k>>3, q = k&7;
    #pragma unroll
    for (int e=0;e<8;e++) s_out[e*320 + h*40 + 16 + q*3 + c] = acc[e];
  }
  if (tid < 64) {
    int e = tid>>3, h = tid&7;
    float lg = logits[(eb+e)*8+h];
    float m  = mx[s_dst[e]*8+h];
    float ex = __expf(lg - m);   // <= 1, never overflows
    s_ex[e*8+h] = ex;
    atomicAdd(&den[s_dst[e]*8+h], ex);
  }
  __syncthreads();

  // P7: scatter numerator
  for (int idx = tid; idx < 2560; idx += 256) {
    int e = idx/320, j = idx - e*320;
    int h = j/40;
    atomicAdd(&num[s_dst[e]*320 + j], s_out[e*320+j]*s_ex[e*8+h]);
  }
}

// ---------------------------------------------------------------- node post
__global__ __launch_bounds__(256) void node_post(
    const float* __restrict__ num, const float* __restrict__ den,
    const float* __restrict__ Wproj_s, const float* __restrict__ bproj,
    const float* __restrict__ Wproj_v, float* __restrict__ out) {
  __shared__ __align__(16) float s_ns[128*8];
  __shared__ __align__(16) float s_nv[192*8];
  const int tid = threadIdx.x;
  const int n0 = blockIdx.x*8;
  for (int idx = tid; idx < 8*320; idx += 256) {
    int n = idx/320, j = idx - n*320;
    int h = j/40, r = j - h*40;
    float a = num[(n0+n)*320+j] / (den[(n0+n)*8+h] + 1e-16f);
    if (r < 16) s_ns[(h*16+r)*8+n] = a;
    else        s_nv[(h*24 + (r-16))*8+n] = a;   // h*24+q == m*3+c
  }
  __syncthreads();
  {
    int g = tid>>7, j = tid&127;
    float acc[4]; float b = bproj[j];
    #pragma unroll
    for (int i=0;i<4;i++) acc[i]=b;
    for (int k=0;k<128;k++) {
      float wv = Wproj_s[k*128+j];
      float4 s4 = *(const float4*)&s_ns[k*8+g*4];
      acc[0]+=s4.x*wv; acc[1]+=s4.y*wv; acc[2]+=s4.z*wv; acc[3]+=s4.w*wv;
    }
    #pragma unroll
    for (int i=0;i<4;i++) out[(n0+g*4+i)*320 + j] = acc[i];
  }
  if (tid < 192) {
    int c = tid>>6, k = tid&63;
    float acc[8];
    #pragma unroll
    for (int e=0;e<8;e++) acc[e]=0.f;
    for (int m=0;m<64;m++) {
      float wv = Wproj_v[m*64+k];
      float4 v0 = *(const float4*)&s_nv[(m*3+c)*8];
      float4 v1 = *(const float4*)&s_nv[(m*3+c)*8+4];
      acc[0]+=v0.x*wv; acc[1]+=v0.y*wv; acc[2]+=v0.z*wv; acc[3]+=v0.w*wv;
      acc[4]+=v1.x*wv; acc[5]+=v1.y*wv; acc[6]+=v1.z*wv; acc[7]+=v1.w*wv;
    }
    #pragma unroll
    for (int e=0;e<8;e++) out[(n0+e)*320 + 128 + k*3 + c] = acc[e];
  }
}

// ---------------------------------------------------------------- launch
extern "C" void kernel_launch(void* const* d_in, const int* in_sizes, int n_in,
                              void* d_out, int out_size, void* d_ws, size_t ws_size,
                              hipStream_t stream) {
  (void)in_sizes; (void)n_in; (void)out_size; (void)ws_size;
  const float* node_input = (const float*)d_in[0];
  const int*   esrc       = (const int*)d_in[1];
  const int*   edst       = (const int*)d_in[2];
  const float* eattr      = (const float*)d_in[3];
  const float* escal      = (const float*)d_in[4];
  const float* Wsrc_s     = (const float*)d_in[5];
  const float* Wsrc_v     = (const float*)d_in[6];
  const float* bsrc       = (const float*)d_in[7];
  const float* Wdst_s     = (const float*)d_in[8];
  const float* Wdst_v     = (const float*)d_in[9];
  const float* rad_W1     = (const float*)d_in[10];
  const float* rad_b1     = (const float*)d_in[11];
  const float* rad_W2     = (const float*)d_in[12];
  const float* rad_off    = (const float*)d_in[13];
  const float* Wact_s     = (const float*)d_in[14];
  const float* bact       = (const float*)d_in[15];
  const float* Wact_v     = (const float*)d_in[16];
  const float* Walpha     = (const float*)d_in[17];
  const float* balpha     = (const float*)d_in[18];
  const float* w_int      = (const float*)d_in[19];
  const float* Wval_s     = (const float*)d_in[20];
  const float* bval       = (const float*)d_in[21];
  const float* Wval_v     = (const float*)d_in[22];
  const float* alpha_dot  = (const float*)d_in[23];
  const float* Wproj_s    = (const float*)d_in[24];
  const float* bproj      = (const float*)d_in[25];
  const float* Wproj_v    = (const float*)d_in[26];
  float* out = (float*)d_out;

  float* ws = (float*)d_ws;
  float* ms_s   = ws;                 // N*128
  float* md_s   = ws + 1280000;       // N*128
  float* ms_v   = ws + 2560000;       // N*192
  float* md_v   = ws + 4480000;       // N*192
  float* logits = ws + 6400000;       // E*8
  float* mx     = ws + 7680000;       // N*8
  float* den    = ws + 7760000;       // N*8
  float* num    = ws + 7840000;       // N*320   (end: 11,040,000 floats = 44.2 MB)

  k_init<<<12500, 256, 0, stream>>>(num, den, (int*)mx);
  node_pre<<<1250, 256, 0, stream>>>(node_input, Wsrc_s, Wsrc_v, bsrc, Wdst_s, Wdst_v,
                                     ms_s, md_s, ms_v, md_v);
  e1_logits<<<20000, 256, 0, stream>>>(ms_s, md_s, ms_v, md_v, esrc, edst, eattr, escal,
                                       rad_W1, rad_b1, rad_W2, rad_off,
                                       Walpha, balpha, alpha_dot, logits);
  e_max<<<5000, 256, 0, stream>>>(logits, edst, mx);
  e2_agg<<<20000, 256, 0, stream>>>(ms_s, md_s, ms_v, md_v, esrc, edst, eattr, escal,
                                    rad_W1, rad_b1, rad_W2, rad_off,
                                    Wact_s, bact, Wact_v, w_int,
                                    Wval_s, bval, Wval_v,
                                    logits, mx, den, num);
  node_post<<<1250, 256, 0, stream>>>(num, den, Wproj_s, bproj, Wproj_v, out);
}

// Round 2
// 1435.571 us; speedup vs baseline: 1.5812x; 1.5812x over previous
//
#include <hip/hip_runtime.h>

#define NN 10000
#define NE 160000
#define INV_SQRT3f 0.57735026918962576f
#define INV_SQRT2f 0.70710678118654752f

__device__ __forceinline__ float sigm(float x){ return 1.f/(1.f+__expf(-x)); }
__device__ __forceinline__ float siluf(float x){ return x*sigm(x); }
__device__ __forceinline__ float sleaky(float x){ return 0.6f*x + 0.4f*x*(2.f*sigm(x)-1.f); }
__device__ __forceinline__ void atomicMaxF(float* a, float v){
  v += 0.0f;
  if (v >= 0.f) atomicMax((int*)a, __float_as_int(v));
  else          atomicMin((unsigned int*)a, __float_as_uint(v));
}

// ---------------------------------------------------------------- init
__global__ __launch_bounds__(256) void k_init(float* __restrict__ num,
                                              float* __restrict__ den,
                                              int* __restrict__ mx) {
  int i = blockIdx.x*256 + threadIdx.x;
  if (i < NN*320) num[i] = 0.f;
  if (i < NN*8) { den[i] = 0.f; mx[i] = 0xFF800000; }
}

// ---------------------------------------------------------------- node pre (unchanged)
__global__ __launch_bounds__(256) void node_pre(
    const float* __restrict__ x,
    const float* __restrict__ Wsrc_s, const float* __restrict__ Wsrc_v,
    const float* __restrict__ bsrc,
    const float* __restrict__ Wdst_s, const float* __restrict__ Wdst_v,
    float* __restrict__ ms_s, float* __restrict__ md_s,
    float* __restrict__ ms_v, float* __restrict__ md_v) {
  __shared__ __align__(16) float s_s[128*8];
  __shared__ __align__(16) float s_v[192*8];
  const int tid = threadIdx.x;
  const int n0 = blockIdx.x*8;
  for (int idx = tid; idx < 8*320; idx += 256) {
    int n = idx/320, d = idx - n*320;
    float val = x[(n0+n)*320 + d];
    if (d < 128) s_s[d*8+n] = val;
    else         s_v[(d-128)*8+n] = val;
  }
  __syncthreads();
  {
    int g = tid>>7, j = tid&127;
    float accs[4], accd[4];
    float b = bsrc[j];
    #pragma unroll
    for (int i=0;i<4;i++){ accs[i]=b; accd[i]=0.f; }
    for (int k=0;k<128;k++) {
      float w1 = Wsrc_s[k*128+j], w2 = Wdst_s[k*128+j];
      float4 sv = *(const float4*)&s_s[k*8+g*4];
      accs[0]+=sv.x*w1; accs[1]+=sv.y*w1; accs[2]+=sv.z*w1; accs[3]+=sv.w*w1;
      accd[0]+=sv.x*w2; accd[1]+=sv.y*w2; accd[2]+=sv.z*w2; accd[3]+=sv.w*w2;
    }
    #pragma unroll
    for (int i=0;i<4;i++){ int n=n0+g*4+i; ms_s[n*128+j]=accs[i]; md_s[n*128+j]=accd[i]; }
  }
  if (tid < 192) {
    int c = tid>>6, k = tid&63;
    float accs[8], accd[8];
    #pragma unroll
    for (int e=0;e<8;e++){ accs[e]=0.f; accd[e]=0.f; }
    for (int m=0;m<64;m++) {
      float w1 = Wsrc_v[m*64+k], w2 = Wdst_v[m*64+k];
      float4 v0 = *(const float4*)&s_v[(m*3+c)*8];
      float4 v1 = *(const float4*)&s_v[(m*3+c)*8+4];
      accs[0]+=v0.x*w1; accs[1]+=v0.y*w1; accs[2]+=v0.z*w1; accs[3]+=v0.w*w1;
      accs[4]+=v1.x*w1; accs[5]+=v1.y*w1; accs[6]+=v1.z*w1; accs[7]+=v1.w*w1;
      accd[0]+=v0.x*w2; accd[1]+=v0.y*w2; accd[2]+=v0.z*w2; accd[3]+=v0.w*w2;
      accd[4]+=v1.x*w2; accd[5]+=v1.y*w2; accd[6]+=v1.z*w2; accd[7]+=v1.w*w2;
    }
    #pragma unroll
    for (int e=0;e<8;e++){ int n=n0+e; ms_v[n*192+k*3+c]=accs[e]; md_v[n*192+k*3+c]=accd[e]; }
  }
}

// ---------------------------------------------------------------- edge pass 1: logits (+segment max fused)
__global__ __launch_bounds__(256) void e1_logits(
    const float* __restrict__ ms_s, const float* __restrict__ md_s,
    const float* __restrict__ ms_v, const float* __restrict__ md_v,
    const int* __restrict__ esrc, const int* __restrict__ edst,
    const float* __restrict__ eattr, const float* __restrict__ escal,
    const float* __restrict__ rad_W1, const float* __restrict__ rad_b1,
    const float* __restrict__ rad_W2, const float* __restrict__ rad_off,
    const float* __restrict__ Walpha, const float* __restrict__ balpha,
    const float* __restrict__ alpha_dot,
    float* __restrict__ logits, float* __restrict__ mx) {
  __shared__ __align__(16) float s_es[256];
  __shared__ __align__(16) float s_h[512];
  __shared__ __align__(16) float s_w[1536];   // rows 0..127 = w1, 128..191 = w4
  __shared__ __align__(16) float s_ds[1536];
  __shared__ __align__(16) float s_p[1024];
  __shared__ float s_e0[8], s_e1[24];
  __shared__ int s_src[8], s_dst[8];
  const int tid = threadIdx.x;
  const int eb = blockIdx.x*8;

  if (tid < 8) { s_src[tid] = esrc[eb+tid]; s_dst[tid] = edst[eb+tid]; }
  if (tid >= 32 && tid < 64) {
    int t = tid-32, e = t>>2, q = t&3;
    float a = eattr[(eb+e)*4+q];
    if (q == 0) s_e0[e] = a; else s_e1[(q-1)*8+e] = a;
  }
  { int e = tid>>5, i = tid&31; s_es[e*32+i] = escal[(eb+e)*32+i]; }
  __syncthreads();

  #pragma unroll
  for (int rep = 0; rep < 2; ++rep) {          // H
    int idx = tid + rep*256;
    int j = idx & 63, e = idx >> 6;
    float acc = rad_b1[j];
    #pragma unroll
    for (int i = 0; i < 32; ++i) acc += s_es[e*32+i]*rad_W1[i*64+j];
    s_h[j*8+e] = siluf(acc);
  }
  __syncthreads();

  if (tid < 192) {                              // w (192 needed cols)
    int jj = tid < 128 ? tid : tid + 192;
    float acc[8]; float o = rad_off[jj];
    #pragma unroll
    for (int e=0;e<8;e++) acc[e]=o;
    for (int k=0;k<64;k++) {
      float wv = rad_W2[k*448+jj];
      float4 h0 = *(const float4*)&s_h[k*8];
      float4 h1 = *(const float4*)&s_h[k*8+4];
      acc[0]+=h0.x*wv; acc[1]+=h0.y*wv; acc[2]+=h0.z*wv; acc[3]+=h0.w*wv;
      acc[4]+=h1.x*wv; acc[5]+=h1.y*wv; acc[6]+=h1.z*wv; acc[7]+=h1.w*wv;
    }
    *(float4*)&s_w[tid*8]   = make_float4(acc[0],acc[1],acc[2],acc[3]);
    *(float4*)&s_w[tid*8+4] = make_float4(acc[4],acc[5],acc[6],acc[7]);
  }
  __syncthreads();

  for (int idx = tid; idx < 1024; idx += 256) { // fused msg_s gather + os1
    int e = idx&7, m = idx>>3;
    float msgs = ms_s[s_src[e]*128+m] + md_s[s_dst[e]*128+m];
    s_ds[m*8+e] = s_w[m*8+e]*msgs*s_e0[e];
  }
  for (int idx = tid; idx < 512; idx += 256) {  // fused msg_v gather + os2
    int e = idx&7, k = idx>>3;
    const float* pa = &ms_v[s_src[e]*192 + k*3];
    const float* pb = &md_v[s_dst[e]*192 + k*3];
    float vx = pa[0]+pb[0], vy = pa[1]+pb[1], vz = pa[2]+pb[2];
    float d = vx*s_e1[0+e] + vy*s_e1[8+e] + vz*s_e1[16+e];
    s_ds[(128+k)*8+e] = s_w[(128+k)*8+e]*d*INV_SQRT3f;
  }
  __syncthreads();

  {                                             // alpha GEMV: 256 tasks = 128 cols x 2 halves
    int g = tid>>7, j = tid&127;
    float acc[4]; float b = balpha[j];
    #pragma unroll
    for (int i=0;i<4;i++) acc[i]=b;
    for (int k=0;k<192;k++) {
      float wv = Walpha[k*128+j];
      float4 d4 = *(const float4*)&s_ds[k*8+g*4];
      acc[0]+=d4.x*wv; acc[1]+=d4.y*wv; acc[2]+=d4.z*wv; acc[3]+=d4.w*wv;
    }
    float ad = alpha_dot[j];
    *(float4*)&s_p[j*8+g*4] = make_float4(sleaky(acc[0])*ad, sleaky(acc[1])*ad,
                                          sleaky(acc[2])*ad, sleaky(acc[3])*ad);
  }
  __syncthreads();

  if (tid < 64) {
    int e = tid>>3, h = tid&7;
    float s = 0.f;
    #pragma unroll
    for (int q=0;q<16;q++) s += s_p[(h*16+q)*8+e];
    logits[(eb+e)*8+h] = s;
    atomicMaxF(&mx[s_dst[e]*8+h], s);
  }
}

// ---------------------------------------------------------------- edge pass 2: value + aggregate
// LDS ~40KB -> 4 blocks/CU. Rank-1 compression of dv/vv rows 0..127.
__global__ __launch_bounds__(256, 4) void e2_agg(
    const float* __restrict__ ms_s, const float* __restrict__ md_s,
    const float* __restrict__ ms_v, const float* __restrict__ md_v,
    const int* __restrict__ esrc, const int* __restrict__ edst,
    const float* __restrict__ eattr, const float* __restrict__ escal,
    const float* __restrict__ rad_W1, const float* __restrict__ rad_b1,
    const float* __restrict__ rad_W2, const float* __restrict__ rad_off,
    const float* __restrict__ Wact_s, const float* __restrict__ bact,
    const float* __restrict__ Wact_v, const float* __restrict__ w_int,
    const float* __restrict__ Wval_s, const float* __restrict__ bval,
    const float* __restrict__ Wval_v,
    const float* __restrict__ logits, const float* __restrict__ mx,
    float* __restrict__ den, float* __restrict__ num) {
  // s_w: w(448x8) | later scal(192x8)@0 + gated(192x8)@1536 | later out(8x320)@0
  __shared__ __align__(16) float s_w[3584];
  // s_d: ds(192x8)@0, t1(128x8)@1536, dvB(384x8)@2560 ; later vs/t2/vvB same layout
  __shared__ __align__(16) float s_d[5632];
  // s_aux: es(256)+h(512) ; later gsh(512)@0 ; later vsh(512)@0 + ex(64)@512
  __shared__ __align__(16) float s_aux[768];
  __shared__ float s_e0[8], s_e1[24];
  __shared__ int s_src[8], s_dst[8];
  const int tid = threadIdx.x;
  const int eb = blockIdx.x*8;

  // P0
  if (tid < 8) { s_src[tid] = esrc[eb+tid]; s_dst[tid] = edst[eb+tid]; }
  if (tid >= 32 && tid < 64) {
    int t = tid-32, e = t>>2, q = t&3;
    float a = eattr[(eb+e)*4+q];
    if (q == 0) s_e0[e] = a; else s_e1[(q-1)*8+e] = a;
  }
  { int e = tid>>5, i = tid&31; s_aux[e*32+i] = escal[(eb+e)*32+i]; }
  __syncthreads();

  // P1: H = silu(es@W1+b1) -> s_aux[256..768)
  #pragma unroll
  for (int rep = 0; rep < 2; ++rep) {
    int idx = tid + rep*256;
    int j = idx & 63, e = idx >> 6;
    float acc = rad_b1[j];
    #pragma unroll
    for (int i = 0; i < 32; ++i) acc += s_aux[e*32+i]*rad_W1[i*64+j];
    s_aux[256 + j*8+e] = siluf(acc);
  }
  __syncthreads();

  // P2: w = H@W2 + off (448 cols)
  for (int j = tid; j < 448; j += 256) {
    float acc[8]; float o = rad_off[j];
    #pragma unroll
    for (int e=0;e<8;e++) acc[e]=o;
    for (int k=0;k<64;k++) {
      float wv = rad_W2[k*448+j];
      float4 h0 = *(const float4*)&s_aux[256+k*8];
      float4 h1 = *(const float4*)&s_aux[256+k*8+4];
      acc[0]+=h0.x*wv; acc[1]+=h0.y*wv; acc[2]+=h0.z*wv; acc[3]+=h0.w*wv;
      acc[4]+=h1.x*wv; acc[5]+=h1.y*wv; acc[6]+=h1.z*wv; acc[7]+=h1.w*wv;
    }
    *(float4*)&s_w[j*8]   = make_float4(acc[0],acc[1],acc[2],acc[3]);
    *(float4*)&s_w[j*8+4] = make_float4(acc[4],acc[5],acc[6],acc[7]);
  }
  __syncthreads();

  // P3a: fused msg_s gather -> ds rows 0..127 (os1) + t1 (rank-1 factor of ov1)
  for (int idx = tid; idx < 1024; idx += 256) {
    int e = idx&7, m = idx>>3;
    float msgs = ms_s[s_src[e]*128+m] + md_s[s_dst[e]*128+m];
    s_d[m*8+e]        = s_w[m*8+e]*msgs*s_e0[e];        // os1 = w1*s*e0
    s_d[1536 + m*8+e] = s_w[(128+m)*8+e]*msgs;          // t1 = w2*s  (ov1 = t1 x e1)
  }
  // P3b: fused msg_v gather -> ds rows 128..191 (os2), dvB: ov2 (q=k), ov3 (q=64+k)
  for (int idx = tid; idx < 512; idx += 256) {
    int e = idx&7, k = idx>>3;
    const float* pa = &ms_v[s_src[e]*192 + k*3];
    const float* pb = &md_v[s_dst[e]*192 + k*3];
    float vx = pa[0]+pb[0], vy = pa[1]+pb[1], vz = pa[2]+pb[2];
    float ex1 = s_e1[0+e], ey1 = s_e1[8+e], ez1 = s_e1[16+e];
    float d = vx*ex1 + vy*ey1 + vz*ez1;
    s_d[(128+k)*8+e] = s_w[(320+k)*8+e]*d*INV_SQRT3f;   // os2
    float w3v = s_w[(256+k)*8+e]*s_e0[e];
    s_d[2560 + (k*3+0)*8+e] = w3v*vx;                    // ov2
    s_d[2560 + (k*3+1)*8+e] = w3v*vy;
    s_d[2560 + (k*3+2)*8+e] = w3v*vz;
    float w5 = s_w[(384+k)*8+e]*INV_SQRT2f;
    s_d[2560 + ((64+k)*3+0)*8+e] = w5*(vy*ez1 - vz*ey1); // ov3
    s_d[2560 + ((64+k)*3+1)*8+e] = w5*(vz*ex1 - vx*ez1);
    s_d[2560 + ((64+k)*3+2)*8+e] = w5*(vx*ey1 - vy*ex1);
  }
  __syncthreads();

  // P4: 448 tasks: scal(192 cols), gA(64: shared part over t1), gB(192: explicit part)
  for (int t = tid; t < 448; t += 256) {
    if (t < 192) {
      int j = t;
      float acc[8]; float b = bact[j];
      #pragma unroll
      for (int e=0;e<8;e++) acc[e]=b;
      for (int k=0;k<192;k++) {
        float wv = Wact_s[k*192+j];
        float4 d0 = *(const float4*)&s_d[k*8];
        float4 d1 = *(const float4*)&s_d[k*8+4];
        acc[0]+=d0.x*wv; acc[1]+=d0.y*wv; acc[2]+=d0.z*wv; acc[3]+=d0.w*wv;
        acc[4]+=d1.x*wv; acc[5]+=d1.y*wv; acc[6]+=d1.z*wv; acc[7]+=d1.w*wv;
      }
      *(float4*)&s_w[j*8]   = make_float4(acc[0],acc[1],acc[2],acc[3]);  // scal
      *(float4*)&s_w[j*8+4] = make_float4(acc[4],acc[5],acc[6],acc[7]);
    } else if (t < 256) {
      int k = t-192;
      float acc[8];
      #pragma unroll
      for (int e=0;e<8;e++) acc[e]=0.f;
      for (int m=0;m<128;m++) {
        float wv = Wact_v[m*64+k];
        float4 d0 = *(const float4*)&s_d[1536+m*8];
        float4 d1 = *(const float4*)&s_d[1536+m*8+4];
        acc[0]+=d0.x*wv; acc[1]+=d0.y*wv; acc[2]+=d0.z*wv; acc[3]+=d0.w*wv;
        acc[4]+=d1.x*wv; acc[5]+=d1.y*wv; acc[6]+=d1.z*wv; acc[7]+=d1.w*wv;
      }
      *(float4*)&s_aux[k*8]   = make_float4(acc[0],acc[1],acc[2],acc[3]); // gsh
      *(float4*)&s_aux[k*8+4] = make_float4(acc[4],acc[5],acc[6],acc[7]);
    } else {
      int tt = t-256, k = tt&63, c = tt>>6;
      float acc[8];
      #pragma unroll
      for (int e=0;e<8;e++) acc[e]=0.f;
      for (int q=0;q<128;q++) {
        float wv = Wact_v[(128+q)*64+k];
        float4 d0 = *(const float4*)&s_d[2560+(q*3+c)*8];
        float4 d1 = *(const float4*)&s_d[2560+(q*3+c)*8+4];
        acc[0]+=d0.x*wv; acc[1]+=d0.y*wv; acc[2]+=d0.z*wv; acc[3]+=d0.w*wv;
        acc[4]+=d1.x*wv; acc[5]+=d1.y*wv; acc[6]+=d1.z*wv; acc[7]+=d1.w*wv;
      }
      int r = k*3+c;
      *(float4*)&s_w[1536+r*8]   = make_float4(acc[0],acc[1],acc[2],acc[3]); // gated explicit part
      *(float4*)&s_w[1536+r*8+4] = make_float4(acc[4],acc[5],acc[6],acc[7]);
    }
  }
  __syncthreads();

  // P5a: val_s + dtp2 scalar-origin rows: vs rows 0..127, t2 (rank-1 factor)
  for (int idx = tid; idx < 1024; idx += 256) {
    int e = idx&7, m = idx>>3;
    float v = siluf(s_w[m*8+e]);
    s_d[m*8+e]        = w_int[m]*v*s_e0[e];
    s_d[1536 + m*8+e] = w_int[128+m]*v;
  }
  // P5b: val_v = (gsh*e1 + gatedB)*sigmoid ; dtp2 vector-origin rows
  for (int idx = tid; idx < 512; idx += 256) {
    int e = idx&7, k = idx>>3;
    float sg = sigm(s_w[(128+k)*8+e]);
    float gs = s_aux[k*8+e];
    float ex1 = s_e1[0+e], ey1 = s_e1[8+e], ez1 = s_e1[16+e];
    float v0 = (gs*ex1 + s_w[1536+(k*3+0)*8+e])*sg;
    float v1 = (gs*ey1 + s_w[1536+(k*3+1)*8+e])*sg;
    float v2 = (gs*ez1 + s_w[1536+(k*3+2)*8+e])*sg;
    float d = v0*ex1 + v1*ey1 + v2*ez1;
    s_d[(128+k)*8+e] = w_int[320+k]*d*INV_SQRT3f;
    float w3v = w_int[256+k]*s_e0[e];
    s_d[2560 + (k*3+0)*8+e] = w3v*v0;
    s_d[2560 + (k*3+1)*8+e] = w3v*v1;
    s_d[2560 + (k*3+2)*8+e] = w3v*v2;
    float w5 = w_int[384+k]*INV_SQRT2f;
    s_d[2560 + ((64+k)*3+0)*8+e] = w5*(v1*ez1 - v2*ey1);
    s_d[2560 + ((64+k)*3+1)*8+e] = w5*(v2*ex1 - v0*ez1);
    s_d[2560 + ((64+k)*3+2)*8+e] = w5*(v0*ey1 - v1*ex1);
  }
  __syncthreads();

  // P6 pass1: val_s GEMV (128), vA shared part (64), ex/den (64 threads)
  {
    int t = tid;
    if (t < 128) {
      int j = t;
      float acc[8]; float b = bval[j];
      #pragma unroll
      for (int e=0;e<8;e++) acc[e]=b;
      for (int k=0;k<192;k++) {
        float wv = Wval_s[k*128+j];
        float4 d0 = *(const float4*)&s_d[k*8];
        float4 d1 = *(const float4*)&s_d[k*8+4];
        acc[0]+=d0.x*wv; acc[1]+=d0.y*wv; acc[2]+=d0.z*wv; acc[3]+=d0.w*wv;
        acc[4]+=d1.x*wv; acc[5]+=d1.y*wv; acc[6]+=d1.z*wv; acc[7]+=d1.w*wv;
      }
      int h = j>>4, jj = j&15;
      #pragma unroll
      for (int e=0;e<8;e++) s_w[e*320 + h*40 + jj] = acc[e];   // out region
    } else if (t < 192) {
      int k = t-128;
      float acc[8];
      #pragma unroll
      for (int e=0;e<8;e++) acc[e]=0.f;
      for (int m=0;m<128;m++) {
        float wv = Wval_v[m*64+k];
        float4 d0 = *(const float4*)&s_d[1536+m*8];
        float4 d1 = *(const float4*)&s_d[1536+m*8+4];
        acc[0]+=d0.x*wv; acc[1]+=d0.y*wv; acc[2]+=d0.z*wv; acc[3]+=d0.w*wv;
        acc[4]+=d1.x*wv; acc[5]+=d1.y*wv; acc[6]+=d1.z*wv; acc[7]+=d1.w*wv;
      }
      *(float4*)&s_aux[k*8]   = make_float4(acc[0],acc[1],acc[2],acc[3]); // vsh
      *(float4*)&s_aux[k*8+4] = make_float4(acc[4],acc[5],acc[6],acc[7]);
    } else {
      int i = t-192, e = i>>3, h = i&7;
      float lg = logits[(eb+e)*8+h];
      float m  = mx[s_dst[e]*8+h];
      float ex = __expf(lg - m);
      s_aux[512 + e*8+h] = ex;
      atomicAdd(&den[s_dst[e]*8+h], ex);
    }
  }
  __syncthreads();

  // P6 pass2: vB explicit part + combine with e1*vsh
  if (tid < 192) {
    int k = tid&63, c = tid>>6;
    float acc[8];
    #pragma unroll
    for (int e=0;e<8;e++) acc[e]=0.f;
    for (int q=0;q<128;q++) {
      float wv = Wval_v[(128+q)*64+k];
      float4 d0 = *(const float4*)&s_d[2560+(q*3+c)*8];
      float4 d1 = *(const float4*)&s_d[2560+(q*3+c)*8+4];
      acc[0]+=d0.x*wv; acc[1]+=d0.y*wv; acc[2]+=d0.z*wv; acc[3]+=d0.w*wv;
      acc[4]+=d1.x*wv; acc[5]+=d1.y*wv; acc[6]+=d1.z*wv; acc[7]+=d1.w*wv;
    }
    int h = k>>3, q = k&7;
    #pragma unroll
    for (int e=0;e<8;e++) {
      float v = acc[e] + s_e1[c*8+e]*s_aux[k*8+e];
      s_w[e*320 + h*40 + 16 + q*3 + c] = v;
    }
  }
  __syncthreads();

  // P7: scatter numerator
  for (int idx = tid; idx < 2560; idx += 256) {
    int e = idx/320, j = idx - e*320;
    int h = j/40;
    atomicAdd(&num[s_dst[e]*320 + j], s_w[e*320+j]*s_aux[512 + e*8+h]);
  }
}

// ---------------------------------------------------------------- node post (unchanged)
__global__ __launch_bounds__(256) void node_post(
    const float* __restrict__ num, const float* __restrict__ den,
    const float* __restrict__ Wproj_s, const float* __restrict__ bproj,
    const float* __restrict__ Wproj_v, float* __restrict__ out) {
  __shared__ __align__(16) float s_ns[128*8];
  __shared__ __align__(16) float s_nv[192*8];
  const int tid = threadIdx.x;
  const int n0 = blockIdx.x*8;
  for (int idx = tid; idx < 8*320; idx += 256) {
    int n = idx/320, j = idx - n*320;
    int h = j/40, r = j - h*40;
    float a = num[(n0+n)*320+j] / (den[(n0+n)*8+h] + 1e-16f);
    if (r < 16) s_ns[(h*16+r)*8+n] = a;
    else        s_nv[(h*24 + (r-16))*8+n] = a;
  }
  __syncthreads();
  {
    int g = tid>>7, j = tid&127;
    float acc[4]; float b = bproj[j];
    #pragma unroll
    for (int i=0;i<4;i++) acc[i]=b;
    for (int k=0;k<128;k++) {
      float wv = Wproj_s[k*128+j];
      float4 s4 = *(const float4*)&s_ns[k*8+g*4];
      acc[0]+=s4.x*wv; acc[1]+=s4.y*wv; acc[2]+=s4.z*wv; acc[3]+=s4.w*wv;
    }
    #pragma unroll
    for (int i=0;i<4;i++) out[(n0+g*4+i)*320 + j] = acc[i];
  }
  if (tid < 192) {
    int c = tid>>6, k = tid&63;
    float acc[8];
    #pragma unroll
    for (int e=0;e<8;e++) acc[e]=0.f;
    for (int m=0;m<64;m++) {
      float wv = Wproj_v[m*64+k];
      float4 v0 = *(const float4*)&s_nv[(m*3+c)*8];
      float4 v1 = *(const float4*)&s_nv[(m*3+c)*8+4];
      acc[0]+=v0.x*wv; acc[1]+=v0.y*wv; acc[2]+=v0.z*wv; acc[3]+=v0.w*wv;
      acc[4]+=v1.x*wv; acc[5]+=v1.y*wv; acc[6]+=v1.z*wv; acc[7]+=v1.w*wv;
    }
    #pragma unroll
    for (int e=0;e<8;e++) out[(n0+e)*320 + 128 + k*3 + c] = acc[e];
  }
}

// ---------------------------------------------------------------- launch
extern "C" void kernel_launch(void* const* d_in, const int* in_sizes, int n_in,
                              void* d_out, int out_size, void* d_ws, size_t ws_size,
                              hipStream_t stream) {
  (void)in_sizes; (void)n_in; (void)out_size; (void)ws_size;
  const float* node_input = (const float*)d_in[0];
  const int*   esrc       = (const int*)d_in[1];
  const int*   edst       = (const int*)d_in[2];
  const float* eattr      = (const float*)d_in[3];
  const float* escal      = (const float*)d_in[4];
  const float* Wsrc_s     = (const float*)d_in[5];
  const float* Wsrc_v     = (const float*)d_in[6];
  const float* bsrc       = (const float*)d_in[7];
  const float* Wdst_s     = (const float*)d_in[8];
  const float* Wdst_v     = (const float*)d_in[9];
  const float* rad_W1     = (const float*)d_in[10];
  const float* rad_b1     = (const float*)d_in[11];
  const float* rad_W2     = (const float*)d_in[12];
  const float* rad_off    = (const float*)d_in[13];
  const float* Wact_s     = (const float*)d_in[14];
  const float* bact       = (const float*)d_in[15];
  const float* Wact_v     = (const float*)d_in[16];
  const float* Walpha     = (const float*)d_in[17];
  const float* balpha     = (const float*)d_in[18];
  const float* w_int      = (const float*)d_in[19];
  const float* Wval_s     = (const float*)d_in[20];
  const float* bval       = (const float*)d_in[21];
  const float* Wval_v     = (const float*)d_in[22];
  const float* alpha_dot  = (const float*)d_in[23];
  const float* Wproj_s    = (const float*)d_in[24];
  const float* bproj      = (const float*)d_in[25];
  const float* Wproj_v    = (const float*)d_in[26];
  float* out = (float*)d_out;

  float* ws = (float*)d_ws;
  float* ms_s   = ws;                 // N*128
  float* md_s   = ws + 1280000;       // N*128
  float* ms_v   = ws + 2560000;       // N*192
  float* md_v   = ws + 4480000;       // N*192
  float* logits = ws + 6400000;       // E*8
  float* mx     = ws + 7680000;       // N*8
  float* den    = ws + 7760000;       // N*8
  float* num    = ws + 7840000;       // N*320

  k_init<<<12500, 256, 0, stream>>>(num, den, (int*)mx);
  node_pre<<<1250, 256, 0, stream>>>(node_input, Wsrc_s, Wsrc_v, bsrc, Wdst_s, Wdst_v,
                                     ms_s, md_s, ms_v, md_v);
  e1_logits<<<20000, 256, 0, stream>>>(ms_s, md_s, ms_v, md_v, esrc, edst, eattr, escal,
                                       rad_W1, rad_b1, rad_W2, rad_off,
                                       Walpha, balpha, alpha_dot, logits, mx);
  e2_agg<<<20000, 256, 0, stream>>>(ms_s, md_s, ms_v, md_v, esrc, edst, eattr, escal,
                                    rad_W1, rad_b1, rad_W2, rad_off,
                                    Wact_s, bact, Wact_v, w_int,
                                    Wval_s, bval, Wval_v,
                                    logits, mx, den, num);
  node_post<<<1250, 256, 0, stream>>>(num, den, Wproj_s, bproj, Wproj_v, out);
}

// Round 3
// 740.009 us; speedup vs baseline: 3.0673x; 1.9399x over previous
//
#include <hip/hip_runtime.h>

#define NN 10000
#define NE 160000
#define INV_SQRT3f 0.57735026918962576f
#define INV_SQRT2f 0.70710678118654752f

typedef short bshort8 __attribute__((ext_vector_type(8)));
typedef float floatx4 __attribute__((ext_vector_type(4)));
#define MFMA16(a,b,c) __builtin_amdgcn_mfma_f32_16x16x32_bf16((a),(b),(c),0,0,0)

__device__ __forceinline__ float sigm(float x){ return 1.f/(1.f+__expf(-x)); }
__device__ __forceinline__ float siluf(float x){ return x*sigm(x); }
__device__ __forceinline__ float sleaky(float x){ return 0.6f*x + 0.4f*x*(2.f*sigm(x)-1.f); }
__device__ __forceinline__ void atomicMaxF(float* a, float v){
  v += 0.0f;
  if (v >= 0.f) atomicMax((int*)a, __float_as_int(v));
  else          atomicMin((unsigned int*)a, __float_as_uint(v));
}
__device__ __forceinline__ unsigned short f2bf(float f){
  unsigned u = __float_as_uint(f);
  u += 0x7FFF + ((u>>16)&1);
  return (unsigned short)(u>>16);
}
__device__ __forceinline__ float bf2f(unsigned short h){
  return __uint_as_float(((unsigned)h)<<16);
}

// swizzled-weight segment offsets (in ushorts)
#define O_W1   0
#define O_W2   2048
#define O_WAS  30720
#define O_WAVT 67584
#define O_WAVB 75776
#define O_WVS  83968
#define O_WVVT 108544
#define O_WVVB 116736
#define SWZ_TOTAL 124928

// ---------------------------------------------------------------- init
__global__ __launch_bounds__(256) void k_init(float* __restrict__ num,
                                              float* __restrict__ den,
                                              int* __restrict__ mx) {
  int i = blockIdx.x*256 + threadIdx.x;
  if (i < NN*320) num[i] = 0.f;
  if (i < NN*8) { den[i] = 0.f; mx[i] = 0xFF800000; }
}

// ---------------------------------------------------------------- weight pre-swizzle to MFMA B-frag layout (bf16)
// slot s -> lane l holds B[kt*32 + quad*8 + j][nt*16 + (l&15)]
__global__ __launch_bounds__(256) void k_prep(
    const float* __restrict__ W1, const float* __restrict__ W2,
    const float* __restrict__ WAs, const float* __restrict__ WAv,
    const float* __restrict__ WVs, const float* __restrict__ WVv,
    unsigned short* __restrict__ swz) {
  int s = blockIdx.x*256 + threadIdx.x;
  if (s >= SWZ_TOTAL) return;
  const float* src; int base, N, KT, rowOff;
  if      (s < 2048)  { base=O_W1;   src=W1;  N=64;  KT=1; rowOff=0; }
  else if (s < 30720) { base=O_W2;   src=W2;  N=448; KT=2; rowOff=0; }
  else if (s < 67584) { base=O_WAS;  src=WAs; N=192; KT=6; rowOff=0; }
  else if (s < 75776) { base=O_WAVT; src=WAv; N=64;  KT=4; rowOff=0; }
  else if (s < 83968) { base=O_WAVB; src=WAv; N=64;  KT=4; rowOff=128; }
  else if (s < 108544){ base=O_WVS;  src=WVs; N=128; KT=6; rowOff=0; }
  else if (s < 116736){ base=O_WVVT; src=WVv; N=64;  KT=4; rowOff=0; }
  else                { base=O_WVVB; src=WVv; N=64;  KT=4; rowOff=128; }
  int loc = s - base;
  int j = loc & 7, l = (loc>>3)&63, kt = (loc>>9)%KT, nt = loc/(512*KT);
  int row = kt*32 + (l>>4)*8 + j + rowOff;
  int col = nt*16 + (l&15);
  swz[s] = f2bf(src[row*N + col]);
}

// ---------------------------------------------------------------- node pre (unchanged)
__global__ __launch_bounds__(256) void node_pre(
    const float* __restrict__ x,
    const float* __restrict__ Wsrc_s, const float* __restrict__ Wsrc_v,
    const float* __restrict__ bsrc,
    const float* __restrict__ Wdst_s, const float* __restrict__ Wdst_v,
    float* __restrict__ ms_s, float* __restrict__ md_s,
    float* __restrict__ ms_v, float* __restrict__ md_v) {
  __shared__ __align__(16) float s_s[128*8];
  __shared__ __align__(16) float s_v[192*8];
  const int tid = threadIdx.x;
  const int n0 = blockIdx.x*8;
  for (int idx = tid; idx < 8*320; idx += 256) {
    int n = idx/320, d = idx - n*320;
    float val = x[(n0+n)*320 + d];
    if (d < 128) s_s[d*8+n] = val;
    else         s_v[(d-128)*8+n] = val;
  }
  __syncthreads();
  {
    int g = tid>>7, j = tid&127;
    float accs[4], accd[4];
    float b = bsrc[j];
    #pragma unroll
    for (int i=0;i<4;i++){ accs[i]=b; accd[i]=0.f; }
    for (int k=0;k<128;k++) {
      float w1 = Wsrc_s[k*128+j], w2 = Wdst_s[k*128+j];
      float4 sv = *(const float4*)&s_s[k*8+g*4];
      accs[0]+=sv.x*w1; accs[1]+=sv.y*w1; accs[2]+=sv.z*w1; accs[3]+=sv.w*w1;
      accd[0]+=sv.x*w2; accd[1]+=sv.y*w2; accd[2]+=sv.z*w2; accd[3]+=sv.w*w2;
    }
    #pragma unroll
    for (int i=0;i<4;i++){ int n=n0+g*4+i; ms_s[n*128+j]=accs[i]; md_s[n*128+j]=accd[i]; }
  }
  if (tid < 192) {
    int c = tid>>6, k = tid&63;
    float accs[8], accd[8];
    #pragma unroll
    for (int e=0;e<8;e++){ accs[e]=0.f; accd[e]=0.f; }
    for (int m=0;m<64;m++) {
      float w1 = Wsrc_v[m*64+k], w2 = Wdst_v[m*64+k];
      float4 v0 = *(const float4*)&s_v[(m*3+c)*8];
      float4 v1 = *(const float4*)&s_v[(m*3+c)*8+4];
      accs[0]+=v0.x*w1; accs[1]+=v0.y*w1; accs[2]+=v0.z*w1; accs[3]+=v0.w*w1;
      accs[4]+=v1.x*w1; accs[5]+=v1.y*w1; accs[6]+=v1.z*w1; accs[7]+=v1.w*w1;
      accd[0]+=v0.x*w2; accd[1]+=v0.y*w2; accd[2]+=v0.z*w2; accd[3]+=v0.w*w2;
      accd[4]+=v1.x*w2; accd[5]+=v1.y*w2; accd[6]+=v1.z*w2; accd[7]+=v1.w*w2;
    }
    #pragma unroll
    for (int e=0;e<8;e++){ int n=n0+e; ms_v[n*192+k*3+c]=accs[e]; md_v[n*192+k*3+c]=accd[e]; }
  }
}

// ---------------------------------------------------------------- edge pass 1: logits (fp32, unchanged from R2)
__global__ __launch_bounds__(256) void e1_logits(
    const float* __restrict__ ms_s, const float* __restrict__ md_s,
    const float* __restrict__ ms_v, const float* __restrict__ md_v,
    const int* __restrict__ esrc, const int* __restrict__ edst,
    const float* __restrict__ eattr, const float* __restrict__ escal,
    const float* __restrict__ rad_W1, const float* __restrict__ rad_b1,
    const float* __restrict__ rad_W2, const float* __restrict__ rad_off,
    const float* __restrict__ Walpha, const float* __restrict__ balpha,
    const float* __restrict__ alpha_dot,
    float* __restrict__ logits, float* __restrict__ mx) {
  __shared__ __align__(16) float s_es[256];
  __shared__ __align__(16) float s_h[512];
  __shared__ __align__(16) float s_w[1536];
  __shared__ __align__(16) float s_ds[1536];
  __shared__ __align__(16) float s_p[1024];
  __shared__ float s_e0[8], s_e1[24];
  __shared__ int s_src[8], s_dst[8];
  const int tid = threadIdx.x;
  const int eb = blockIdx.x*8;

  if (tid < 8) { s_src[tid] = esrc[eb+tid]; s_dst[tid] = edst[eb+tid]; }
  if (tid >= 32 && tid < 64) {
    int t = tid-32, e = t>>2, q = t&3;
    float a = eattr[(eb+e)*4+q];
    if (q == 0) s_e0[e] = a; else s_e1[(q-1)*8+e] = a;
  }
  { int e = tid>>5, i = tid&31; s_es[e*32+i] = escal[(eb+e)*32+i]; }
  __syncthreads();

  #pragma unroll
  for (int rep = 0; rep < 2; ++rep) {
    int idx = tid + rep*256;
    int j = idx & 63, e = idx >> 6;
    float acc = rad_b1[j];
    #pragma unroll
    for (int i = 0; i < 32; ++i) acc += s_es[e*32+i]*rad_W1[i*64+j];
    s_h[j*8+e] = siluf(acc);
  }
  __syncthreads();

  if (tid < 192) {
    int jj = tid < 128 ? tid : tid + 192;
    float acc[8]; float o = rad_off[jj];
    #pragma unroll
    for (int e=0;e<8;e++) acc[e]=o;
    for (int k=0;k<64;k++) {
      float wv = rad_W2[k*448+jj];
      float4 h0 = *(const float4*)&s_h[k*8];
      float4 h1 = *(const float4*)&s_h[k*8+4];
      acc[0]+=h0.x*wv; acc[1]+=h0.y*wv; acc[2]+=h0.z*wv; acc[3]+=h0.w*wv;
      acc[4]+=h1.x*wv; acc[5]+=h1.y*wv; acc[6]+=h1.z*wv; acc[7]+=h1.w*wv;
    }
    *(float4*)&s_w[tid*8]   = make_float4(acc[0],acc[1],acc[2],acc[3]);
    *(float4*)&s_w[tid*8+4] = make_float4(acc[4],acc[5],acc[6],acc[7]);
  }
  __syncthreads();

  for (int idx = tid; idx < 1024; idx += 256) {
    int e = idx&7, m = idx>>3;
    float msgs = ms_s[s_src[e]*128+m] + md_s[s_dst[e]*128+m];
    s_ds[m*8+e] = s_w[m*8+e]*msgs*s_e0[e];
  }
  for (int idx = tid; idx < 512; idx += 256) {
    int e = idx&7, k = idx>>3;
    const float* pa = &ms_v[s_src[e]*192 + k*3];
    const float* pb = &md_v[s_dst[e]*192 + k*3];
    float vx = pa[0]+pb[0], vy = pa[1]+pb[1], vz = pa[2]+pb[2];
    float d = vx*s_e1[0+e] + vy*s_e1[8+e] + vz*s_e1[16+e];
    s_ds[(128+k)*8+e] = s_w[(128+k)*8+e]*d*INV_SQRT3f;
  }
  __syncthreads();

  {
    int g = tid>>7, j = tid&127;
    float acc[4]; float b = balpha[j];
    #pragma unroll
    for (int i=0;i<4;i++) acc[i]=b;
    for (int k=0;k<192;k++) {
      float wv = Walpha[k*128+j];
      float4 d4 = *(const float4*)&s_ds[k*8+g*4];
      acc[0]+=d4.x*wv; acc[1]+=d4.y*wv; acc[2]+=d4.z*wv; acc[3]+=d4.w*wv;
    }
    float ad = alpha_dot[j];
    *(float4*)&s_p[j*8+g*4] = make_float4(sleaky(acc[0])*ad, sleaky(acc[1])*ad,
                                          sleaky(acc[2])*ad, sleaky(acc[3])*ad);
  }
  __syncthreads();

  if (tid < 64) {
    int e = tid>>3, h = tid&7;
    float s = 0.f;
    #pragma unroll
    for (int q=0;q<16;q++) s += s_p[(h*16+q)*8+e];
    logits[(eb+e)*8+h] = s;
    atomicMaxF(&mx[s_dst[e]*8+h], s);
  }
}

// ---------------------------------------------------------------- edge pass 2: MFMA value pipeline, 16 edges/block
__global__ __launch_bounds__(256) void e2_agg(
    const float* __restrict__ ms_s, const float* __restrict__ md_s,
    const float* __restrict__ ms_v, const float* __restrict__ md_v,
    const int* __restrict__ esrc, const int* __restrict__ edst,
    const float* __restrict__ eattr, const float* __restrict__ escal,
    const float* __restrict__ rad_b1, const float* __restrict__ rad_off,
    const float* __restrict__ bact, const float* __restrict__ w_int,
    const float* __restrict__ bval,
    const unsigned short* __restrict__ swz,
    const float* __restrict__ logits, const float* __restrict__ mx,
    float* __restrict__ den, float* __restrict__ num) {
  __shared__ __align__(16) char smem[65152];
  // region map (byte offsets). Lifetimes commented; aliasing is deliberate.
  unsigned short* sw  = (unsigned short*)smem;            // 16x448 bf16 (A2->B)
  float* scalf = (float*)smem;                            // 16x192 (C->D)
  float* gshf  = (float*)(smem+12288);                    // 16x64  (C->D)
  float* gbf   = (float*)(smem+16384);                    // 3x16x64(C->D)
  float* soutf = (float*)smem;                            // 16x320 (E->end)
  float* vshf  = (float*)(smem+20480);                    // 16x64  (E->F)
  float* vbf   = (float*)(smem+24576);                    // 3x16x64(E->F)
  unsigned short* ads  = (unsigned short*)(smem+36864);   // 16x200 bf16 A (ds / vs)
  unsigned short* at1  = (unsigned short*)(smem+43264);   // 16x136 bf16 A (t1 / t2)
  unsigned short* advb = (unsigned short*)(smem+47616);   // 3x16x136 bf16 A (dvB / vvB)
  unsigned short* aes  = (unsigned short*)(smem+60672);   // 16x40 bf16 A (escal)
  unsigned short* ah   = (unsigned short*)(smem+61952);   // 16x72 bf16 A (silu h)
  float* s_e0 = (float*)(smem+64256);                     // 16
  float* s_e1 = (float*)(smem+64320);                     // 48 [c*16+e]
  float* s_ex = (float*)(smem+64512);                     // 128
  int* s_src  = (int*)(smem+65024);                       // 16
  int* s_dst  = (int*)(smem+65088);                       // 16
  const int tid  = threadIdx.x;
  const int lane = tid & 63, wave = tid >> 6;
  const int quad = lane >> 4, l15 = lane & 15;
  const int eb = blockIdx.x*16;

  // ---- A0: indices, attr, escal -> bf16 A-matrix
  if (tid < 16) { s_src[tid] = esrc[eb+tid]; s_dst[tid] = edst[eb+tid]; }
  if (tid >= 64 && tid < 128) {
    int t = tid-64, e = t>>2, q = t&3;
    float a = eattr[(eb+e)*4+q];
    if (q == 0) s_e0[e] = a; else s_e1[(q-1)*16+e] = a;
  }
  #pragma unroll
  for (int it = 0; it < 2; ++it) {
    int idx = tid + it*256;
    int e = idx>>5, i = idx&31;
    aes[e*40+i] = f2bf(escal[(eb+e)*32+i]);
  }
  __syncthreads();

  // ---- A1: h = silu(escal@W1 + b1) via MFMA (K=32), one n-tile per wave
  {
    int nt = wave, col = nt*16 + l15;
    bshort8 a = *(const bshort8*)&aes[l15*40 + quad*8];
    bshort8 b = *(const bshort8*)&swz[O_W1 + (nt*64 + lane)*8];
    float bb = rad_b1[col];
    floatx4 acc = {bb,bb,bb,bb};
    acc = MFMA16(a, b, acc);
    #pragma unroll
    for (int r=0;r<4;r++) ah[(quad*4+r)*72 + col] = f2bf(siluf(acc[r]));
  }
  __syncthreads();

  // ---- A2: w = h@W2 + off (448 cols), 7 n-tiles per wave, K=64
  {
    bshort8 ha0 = *(const bshort8*)&ah[l15*72 + quad*8];
    bshort8 ha1 = *(const bshort8*)&ah[l15*72 + 32 + quad*8];
    #pragma unroll
    for (int t=0;t<7;t++) {
      int nt = wave*7 + t, col = nt*16 + l15;
      float o = rad_off[col];
      floatx4 acc = {o,o,o,o};
      acc = MFMA16(ha0, *(const bshort8*)&swz[O_W2 + ((nt*2+0)*64+lane)*8], acc);
      acc = MFMA16(ha1, *(const bshort8*)&swz[O_W2 + ((nt*2+1)*64+lane)*8], acc);
      #pragma unroll
      for (int r=0;r<4;r++) sw[(quad*4+r)*448 + col] = f2bf(acc[r]);
    }
  }
  __syncthreads();

  // ---- B: dtp1 elementwise + gather -> bf16 A-matrices ds, t1, dvB
  #pragma unroll
  for (int it = 0; it < 8; ++it) {
    int t = tid + it*256;
    int m = t&127, e = t>>7;
    float msgs = ms_s[s_src[e]*128+m] + md_s[s_dst[e]*128+m];
    ads[e*200+m] = f2bf(bf2f(sw[e*448+m])*msgs*s_e0[e]);      // os1
    at1[e*136+m] = f2bf(bf2f(sw[e*448+128+m])*msgs);          // t1 = w2*s
  }
  #pragma unroll
  for (int it = 0; it < 4; ++it) {
    int t = tid + it*256;
    int k = t&63, e = t>>6;
    const float* pa = &ms_v[s_src[e]*192 + k*3];
    const float* pb = &md_v[s_dst[e]*192 + k*3];
    float vx = pa[0]+pb[0], vy = pa[1]+pb[1], vz = pa[2]+pb[2];
    float ex1 = s_e1[0+e], ey1 = s_e1[16+e], ez1 = s_e1[32+e];
    float d = vx*ex1 + vy*ey1 + vz*ez1;
    ads[e*200+128+k] = f2bf(bf2f(sw[e*448+320+k])*d*INV_SQRT3f);  // os2
    float w3v = bf2f(sw[e*448+256+k])*s_e0[e];
    float w5  = bf2f(sw[e*448+384+k])*INV_SQRT2f;
    advb[0*2176 + e*136 + k] = f2bf(w3v*vx);
    advb[1*2176 + e*136 + k] = f2bf(w3v*vy);
    advb[2*2176 + e*136 + k] = f2bf(w3v*vz);
    advb[0*2176 + e*136 + 64+k] = f2bf(w5*(vy*ez1 - vz*ey1));
    advb[1*2176 + e*136 + 64+k] = f2bf(w5*(vz*ex1 - vx*ez1));
    advb[2*2176 + e*136 + 64+k] = f2bf(w5*(vx*ey1 - vy*ex1));
  }
  __syncthreads();

  // ---- C: MFMA set 1: scal = ds@Wact_s + bact ; gsh = t1@WAv[0:128] ; gB_c = dvB_c@WAv[128:256]
  {
    bshort8 fa[6];
    #pragma unroll
    for (int kt=0;kt<6;kt++) fa[kt] = *(const bshort8*)&ads[l15*200 + kt*32 + quad*8];
    #pragma unroll
    for (int t=0;t<3;t++) {
      int nt = wave + 4*t, col = nt*16 + l15;
      float bb = bact[col];
      floatx4 acc = {bb,bb,bb,bb};
      #pragma unroll
      for (int kt=0;kt<6;kt++)
        acc = MFMA16(fa[kt], *(const bshort8*)&swz[O_WAS + ((nt*6+kt)*64+lane)*8], acc);
      #pragma unroll
      for (int r=0;r<4;r++) scalf[(quad*4+r)*192 + col] = acc[r];
    }
    bshort8 ft[4];
    #pragma unroll
    for (int kt=0;kt<4;kt++) ft[kt] = *(const bshort8*)&at1[l15*136 + kt*32 + quad*8];
    {
      int nt = wave, col = nt*16 + l15;
      floatx4 acc = {0.f,0.f,0.f,0.f};
      #pragma unroll
      for (int kt=0;kt<4;kt++)
        acc = MFMA16(ft[kt], *(const bshort8*)&swz[O_WAVT + ((nt*4+kt)*64+lane)*8], acc);
      #pragma unroll
      for (int r=0;r<4;r++) gshf[(quad*4+r)*64 + col] = acc[r];
    }
    #pragma unroll
    for (int c=0;c<3;c++) {
      int nt = wave, col = nt*16 + l15;
      floatx4 acc = {0.f,0.f,0.f,0.f};
      #pragma unroll
      for (int kt=0;kt<4;kt++) {
        bshort8 fb = *(const bshort8*)&advb[c*2176 + l15*136 + kt*32 + quad*8];
        acc = MFMA16(fb, *(const bshort8*)&swz[O_WAVB + ((nt*4+kt)*64+lane)*8], acc);
      }
      #pragma unroll
      for (int r=0;r<4;r++) gbf[c*1024 + (quad*4+r)*64 + col] = acc[r];
    }
  }
  __syncthreads();

  // ---- D: activations + dtp2 elementwise -> bf16 A-matrices vs, t2, vvB (reuse ads/at1/advb)
  #pragma unroll
  for (int it = 0; it < 8; ++it) {
    int t = tid + it*256;
    int m = t&127, e = t>>7;
    float v = siluf(scalf[e*192+m]);
    ads[e*200+m] = f2bf(w_int[m]*v*s_e0[e]);
    at1[e*136+m] = f2bf(w_int[128+m]*v);
  }
  #pragma unroll
  for (int it = 0; it < 4; ++it) {
    int t = tid + it*256;
    int k = t&63, e = t>>6;
    float sg = sigm(scalf[e*192+128+k]);
    float gs = gshf[e*64+k];
    float ex1 = s_e1[0+e], ey1 = s_e1[16+e], ez1 = s_e1[32+e];
    float v0 = (gs*ex1 + gbf[0*1024 + e*64+k])*sg;
    float v1 = (gs*ey1 + gbf[1*1024 + e*64+k])*sg;
    float v2 = (gs*ez1 + gbf[2*1024 + e*64+k])*sg;
    float d = v0*ex1 + v1*ey1 + v2*ez1;
    ads[e*200+128+k] = f2bf(w_int[320+k]*d*INV_SQRT3f);
    float w3v = w_int[256+k]*s_e0[e];
    float w5  = w_int[384+k]*INV_SQRT2f;
    advb[0*2176 + e*136 + k] = f2bf(w3v*v0);
    advb[1*2176 + e*136 + k] = f2bf(w3v*v1);
    advb[2*2176 + e*136 + k] = f2bf(w3v*v2);
    advb[0*2176 + e*136 + 64+k] = f2bf(w5*(v1*ez1 - v2*ey1));
    advb[1*2176 + e*136 + 64+k] = f2bf(w5*(v2*ex1 - v0*ez1));
    advb[2*2176 + e*136 + 64+k] = f2bf(w5*(v0*ey1 - v1*ex1));
  }
  __syncthreads();

  // ---- E: MFMA set 2: out_s = vs@Wval_s + bval ; vsh = t2@WVv[0:128] ; vB_c = vvB_c@WVv[128:256]
  {
    bshort8 fa[6];
    #pragma unroll
    for (int kt=0;kt<6;kt++) fa[kt] = *(const bshort8*)&ads[l15*200 + kt*32 + quad*8];
    #pragma unroll
    for (int t=0;t<2;t++) {
      int nt = wave + 4*t, col = nt*16 + l15;    // nt == h for out_s
      float bb = bval[col];
      floatx4 acc = {bb,bb,bb,bb};
      #pragma unroll
      for (int kt=0;kt<6;kt++)
        acc = MFMA16(fa[kt], *(const bshort8*)&swz[O_WVS + ((nt*6+kt)*64+lane)*8], acc);
      #pragma unroll
      for (int r=0;r<4;r++) soutf[(quad*4+r)*320 + nt*40 + l15] = acc[r];
    }
    bshort8 ft[4];
    #pragma unroll
    for (int kt=0;kt<4;kt++) ft[kt] = *(const bshort8*)&at1[l15*136 + kt*32 + quad*8];
    {
      int nt = wave, col = nt*16 + l15;
      floatx4 acc = {0.f,0.f,0.f,0.f};
      #pragma unroll
      for (int kt=0;kt<4;kt++)
        acc = MFMA16(ft[kt], *(const bshort8*)&swz[O_WVVT + ((nt*4+kt)*64+lane)*8], acc);
      #pragma unroll
      for (int r=0;r<4;r++) vshf[(quad*4+r)*64 + col] = acc[r];
    }
    #pragma unroll
    for (int c=0;c<3;c++) {
      int nt = wave, col = nt*16 + l15;
      floatx4 acc = {0.f,0.f,0.f,0.f};
      #pragma unroll
      for (int kt=0;kt<4;kt++) {
        bshort8 fb = *(const bshort8*)&advb[c*2176 + l15*136 + kt*32 + quad*8];
        acc = MFMA16(fb, *(const bshort8*)&swz[O_WVVB + ((nt*4+kt)*64+lane)*8], acc);
      }
      #pragma unroll
      for (int r=0;r<4;r++) vbf[c*1024 + (quad*4+r)*64 + col] = acc[r];
    }
  }
  __syncthreads();

  // ---- F: combine vector outputs; softmax weight; scatter
  #pragma unroll
  for (int it = 0; it < 4; ++it) {
    int t = tid + it*256;
    int k = t&63, e = t>>6;
    float vs_ = vshf[e*64+k];
    int base = e*320 + (k>>3)*40 + 16 + (k&7)*3;
    #pragma unroll
    for (int c=0;c<3;c++)
      soutf[base + c] = vbf[c*1024 + e*64 + k] + s_e1[c*16+e]*vs_;
  }
  if (tid < 128) {
    int e = tid>>3, h = tid&7;
    float lg = logits[(eb+e)*8+h];
    float m  = mx[s_dst[e]*8+h];
    float ex = __expf(lg - m);
    s_ex[e*8+h] = ex;
    atomicAdd(&den[s_dst[e]*8+h], ex);
  }
  __syncthreads();

  for (int idx = tid; idx < 5120; idx += 256) {
    int e = idx/320, j = idx - e*320;
    int h = j/40;
    atomicAdd(&num[s_dst[e]*320 + j], soutf[e*320+j]*s_ex[e*8+h]);
  }
}

// ---------------------------------------------------------------- node post (unchanged)
__global__ __launch_bounds__(256) void node_post(
    const float* __restrict__ num, const float* __restrict__ den,
    const float* __restrict__ Wproj_s, const float* __restrict__ bproj,
    const float* __restrict__ Wproj_v, float* __restrict__ out) {
  __shared__ __align__(16) float s_ns[128*8];
  __shared__ __align__(16) float s_nv[192*8];
  const int tid = threadIdx.x;
  const int n0 = blockIdx.x*8;
  for (int idx = tid; idx < 8*320; idx += 256) {
    int n = idx/320, j = idx - n*320;
    int h = j/40, r = j - h*40;
    float a = num[(n0+n)*320+j] / (den[(n0+n)*8+h] + 1e-16f);
    if (r < 16) s_ns[(h*16+r)*8+n] = a;
    else        s_nv[(h*24 + (r-16))*8+n] = a;
  }
  __syncthreads();
  {
    int g = tid>>7, j = tid&127;
    float acc[4]; float b = bproj[j];
    #pragma unroll
    for (int i=0;i<4;i++) acc[i]=b;
    for (int k=0;k<128;k++) {
      float wv = Wproj_s[k*128+j];
      float4 s4 = *(const float4*)&s_ns[k*8+g*4];
      acc[0]+=s4.x*wv; acc[1]+=s4.y*wv; acc[2]+=s4.z*wv; acc[3]+=s4.w*wv;
    }
    #pragma unroll
    for (int i=0;i<4;i++) out[(n0+g*4+i)*320 + j] = acc[i];
  }
  if (tid < 192) {
    int c = tid>>6, k = tid&63;
    float acc[8];
    #pragma unroll
    for (int e=0;e<8;e++) acc[e]=0.f;
    for (int m=0;m<64;m++) {
      float wv = Wproj_v[m*64+k];
      float4 v0 = *(const float4*)&s_nv[(m*3+c)*8];
      float4 v1 = *(const float4*)&s_nv[(m*3+c)*8+4];
      acc[0]+=v0.x*wv; acc[1]+=v0.y*wv; acc[2]+=v0.z*wv; acc[3]+=v0.w*wv;
      acc[4]+=v1.x*wv; acc[5]+=v1.y*wv; acc[6]+=v1.z*wv; acc[7]+=v1.w*wv;
    }
    #pragma unroll
    for (int e=0;e<8;e++) out[(n0+e)*320 + 128 + k*3 + c] = acc[e];
  }
}

// ---------------------------------------------------------------- launch
extern "C" void kernel_launch(void* const* d_in, const int* in_sizes, int n_in,
                              void* d_out, int out_size, void* d_ws, size_t ws_size,
                              hipStream_t stream) {
  (void)in_sizes; (void)n_in; (void)out_size; (void)ws_size;
  const float* node_input = (const float*)d_in[0];
  const int*   esrc       = (const int*)d_in[1];
  const int*   edst       = (const int*)d_in[2];
  const float* eattr      = (const float*)d_in[3];
  const float* escal      = (const float*)d_in[4];
  const float* Wsrc_s     = (const float*)d_in[5];
  const float* Wsrc_v     = (const float*)d_in[6];
  const float* bsrc       = (const float*)d_in[7];
  const float* Wdst_s     = (const float*)d_in[8];
  const float* Wdst_v     = (const float*)d_in[9];
  const float* rad_W1     = (const float*)d_in[10];
  const float* rad_b1     = (const float*)d_in[11];
  const float* rad_W2     = (const float*)d_in[12];
  const float* rad_off    = (const float*)d_in[13];
  const float* Wact_s     = (const float*)d_in[14];
  const float* bact       = (const float*)d_in[15];
  const float* Wact_v     = (const float*)d_in[16];
  const float* Walpha     = (const float*)d_in[17];
  const float* balpha     = (const float*)d_in[18];
  const float* w_int      = (const float*)d_in[19];
  const float* Wval_s     = (const float*)d_in[20];
  const float* bval       = (const float*)d_in[21];
  const float* Wval_v     = (const float*)d_in[22];
  const float* alpha_dot  = (const float*)d_in[23];
  const float* Wproj_s    = (const float*)d_in[24];
  const float* bproj      = (const float*)d_in[25];
  const float* Wproj_v    = (const float*)d_in[26];
  float* out = (float*)d_out;

  float* ws = (float*)d_ws;
  float* ms_s   = ws;                 // N*128
  float* md_s   = ws + 1280000;       // N*128
  float* ms_v   = ws + 2560000;       // N*192
  float* md_v   = ws + 4480000;       // N*192
  float* logits = ws + 6400000;       // E*8
  float* mx     = ws + 7680000;       // N*8
  float* den    = ws + 7760000;       // N*8
  float* num    = ws + 7840000;       // N*320  -> ends 11,040,000 floats
  unsigned short* swz = (unsigned short*)(ws + 11040000);  // 124,928 ushorts

  k_prep<<<488, 256, 0, stream>>>(rad_W1, rad_W2, Wact_s, Wact_v, Wval_s, Wval_v, swz);
  k_init<<<12500, 256, 0, stream>>>(num, den, (int*)mx);
  node_pre<<<1250, 256, 0, stream>>>(node_input, Wsrc_s, Wsrc_v, bsrc, Wdst_s, Wdst_v,
                                     ms_s, md_s, ms_v, md_v);
  e1_logits<<<20000, 256, 0, stream>>>(ms_s, md_s, ms_v, md_v, esrc, edst, eattr, escal,
                                       rad_W1, rad_b1, rad_W2, rad_off,
                                       Walpha, balpha, alpha_dot, logits, mx);
  e2_agg<<<10000, 256, 0, stream>>>(ms_s, md_s, ms_v, md_v, esrc, edst, eattr, escal,
                                    rad_b1, rad_off, bact, w_int, bval,
                                    swz, logits, mx, den, num);
  node_post<<<1250, 256, 0, stream>>>(num, den, Wproj_s, bproj, Wproj_v, out);
}

// Round 4
// 534.124 us; speedup vs baseline: 4.2497x; 1.3855x over previous
//
#include <hip/hip_runtime.h>

#define NN 10000
#define NE 160000
#define INV_SQRT3f 0.57735026918962576f
#define INV_SQRT2f 0.70710678118654752f

typedef short bshort8 __attribute__((ext_vector_type(8)));
typedef float floatx4 __attribute__((ext_vector_type(4)));
#define MFMA16(a,b,c) __builtin_amdgcn_mfma_f32_16x16x32_bf16((a),(b),(c),0,0,0)

__device__ __forceinline__ float sigm(float x){ return 1.f/(1.f+__expf(-x)); }
__device__ __forceinline__ float siluf(float x){ return x*sigm(x); }
__device__ __forceinline__ float sleaky(float x){ return 0.6f*x + 0.4f*x*(2.f*sigm(x)-1.f); }
__device__ __forceinline__ void atomicMaxF(float* a, float v){
  v += 0.0f;
  if (v >= 0.f) atomicMax((int*)a, __float_as_int(v));
  else          atomicMin((unsigned int*)a, __float_as_uint(v));
}
__device__ __forceinline__ unsigned short f2bf(float f){
  unsigned u = __float_as_uint(f);
  u += 0x7FFF + ((u>>16)&1);
  return (unsigned short)(u>>16);
}
__device__ __forceinline__ float bf2f(unsigned short h){
  return __uint_as_float(((unsigned)h)<<16);
}

// swizzled-weight segment offsets (in ushorts)
#define O_W1   0
#define O_W2   2048
#define O_WAS  30720
#define O_WAVT 67584
#define O_WAVB 75776
#define O_WVS  83968
#define O_WVVT 108544
#define O_WVVB 116736
#define O_WALP 124928
#define SWZ_TOTAL 149504

// ---------------------------------------------------------------- init
__global__ __launch_bounds__(256) void k_init(float* __restrict__ num,
                                              float* __restrict__ den,
                                              int* __restrict__ mx) {
  int i = blockIdx.x*256 + threadIdx.x;
  if (i < NN*320) num[i] = 0.f;
  if (i < NN*8) { den[i] = 0.f; mx[i] = 0xFF800000; }
}

// ---------------------------------------------------------------- weight pre-swizzle to MFMA B-frag layout (bf16)
// slot s -> lane l holds B[kt*32 + quad*8 + j][nt*16 + (l&15)]
__global__ __launch_bounds__(256) void k_prep(
    const float* __restrict__ W1, const float* __restrict__ W2,
    const float* __restrict__ WAs, const float* __restrict__ WAv,
    const float* __restrict__ WVs, const float* __restrict__ WVv,
    const float* __restrict__ WAl,
    unsigned short* __restrict__ swz) {
  int s = blockIdx.x*256 + threadIdx.x;
  if (s >= SWZ_TOTAL) return;
  const float* src; int base, N, KT, rowOff;
  if      (s < 2048)  { base=O_W1;   src=W1;  N=64;  KT=1; rowOff=0; }
  else if (s < 30720) { base=O_W2;   src=W2;  N=448; KT=2; rowOff=0; }
  else if (s < 67584) { base=O_WAS;  src=WAs; N=192; KT=6; rowOff=0; }
  else if (s < 75776) { base=O_WAVT; src=WAv; N=64;  KT=4; rowOff=0; }
  else if (s < 83968) { base=O_WAVB; src=WAv; N=64;  KT=4; rowOff=128; }
  else if (s < 108544){ base=O_WVS;  src=WVs; N=128; KT=6; rowOff=0; }
  else if (s < 116736){ base=O_WVVT; src=WVv; N=64;  KT=4; rowOff=0; }
  else if (s < 124928){ base=O_WVVB; src=WVv; N=64;  KT=4; rowOff=128; }
  else                { base=O_WALP; src=WAl; N=128; KT=6; rowOff=0; }
  int loc = s - base;
  int j = loc & 7, l = (loc>>3)&63, kt = (loc>>9)%KT, nt = loc/(512*KT);
  int row = kt*32 + (l>>4)*8 + j + rowOff;
  int col = nt*16 + (l&15);
  swz[s] = f2bf(src[row*N + col]);
}

// ---------------------------------------------------------------- node pre (unchanged)
__global__ __launch_bounds__(256) void node_pre(
    const float* __restrict__ x,
    const float* __restrict__ Wsrc_s, const float* __restrict__ Wsrc_v,
    const float* __restrict__ bsrc,
    const float* __restrict__ Wdst_s, const float* __restrict__ Wdst_v,
    float* __restrict__ ms_s, float* __restrict__ md_s,
    float* __restrict__ ms_v, float* __restrict__ md_v) {
  __shared__ __align__(16) float s_s[128*8];
  __shared__ __align__(16) float s_v[192*8];
  const int tid = threadIdx.x;
  const int n0 = blockIdx.x*8;
  for (int idx = tid; idx < 8*320; idx += 256) {
    int n = idx/320, d = idx - n*320;
    float val = x[(n0+n)*320 + d];
    if (d < 128) s_s[d*8+n] = val;
    else         s_v[(d-128)*8+n] = val;
  }
  __syncthreads();
  {
    int g = tid>>7, j = tid&127;
    float accs[4], accd[4];
    float b = bsrc[j];
    #pragma unroll
    for (int i=0;i<4;i++){ accs[i]=b; accd[i]=0.f; }
    for (int k=0;k<128;k++) {
      float w1 = Wsrc_s[k*128+j], w2 = Wdst_s[k*128+j];
      float4 sv = *(const float4*)&s_s[k*8+g*4];
      accs[0]+=sv.x*w1; accs[1]+=sv.y*w1; accs[2]+=sv.z*w1; accs[3]+=sv.w*w1;
      accd[0]+=sv.x*w2; accd[1]+=sv.y*w2; accd[2]+=sv.z*w2; accd[3]+=sv.w*w2;
    }
    #pragma unroll
    for (int i=0;i<4;i++){ int n=n0+g*4+i; ms_s[n*128+j]=accs[i]; md_s[n*128+j]=accd[i]; }
  }
  if (tid < 192) {
    int c = tid>>6, k = tid&63;
    float accs[8], accd[8];
    #pragma unroll
    for (int e=0;e<8;e++){ accs[e]=0.f; accd[e]=0.f; }
    for (int m=0;m<64;m++) {
      float w1 = Wsrc_v[m*64+k], w2 = Wdst_v[m*64+k];
      float4 v0 = *(const float4*)&s_v[(m*3+c)*8];
      float4 v1 = *(const float4*)&s_v[(m*3+c)*8+4];
      accs[0]+=v0.x*w1; accs[1]+=v0.y*w1; accs[2]+=v0.z*w1; accs[3]+=v0.w*w1;
      accs[4]+=v1.x*w1; accs[5]+=v1.y*w1; accs[6]+=v1.z*w1; accs[7]+=v1.w*w1;
      accd[0]+=v0.x*w2; accd[1]+=v0.y*w2; accd[2]+=v0.z*w2; accd[3]+=v0.w*w2;
      accd[4]+=v1.x*w2; accd[5]+=v1.y*w2; accd[6]+=v1.z*w2; accd[7]+=v1.w*w2;
    }
    #pragma unroll
    for (int e=0;e<8;e++){ int n=n0+e; ms_v[n*192+k*3+c]=accs[e]; md_v[n*192+k*3+c]=accd[e]; }
  }
}

// ---------------------------------------------------------------- edge pass 1: logits via MFMA, 16 edges/block
__global__ __launch_bounds__(256) void e1_logits(
    const float* __restrict__ ms_s, const float* __restrict__ md_s,
    const float* __restrict__ ms_v, const float* __restrict__ md_v,
    const int* __restrict__ esrc, const int* __restrict__ edst,
    const float* __restrict__ eattr, const float* __restrict__ escal,
    const float* __restrict__ rad_b1, const float* __restrict__ rad_off,
    const float* __restrict__ balpha, const float* __restrict__ alpha_dot,
    const unsigned short* __restrict__ swz,
    float* __restrict__ logits, float* __restrict__ mx) {
  __shared__ __align__(16) unsigned short aes[16*40];   // escal A
  __shared__ __align__(16) unsigned short ah[16*72];    // silu(h) A
  __shared__ __align__(16) unsigned short sw[16*192];   // w1(0..127) + w4(128..191)
  __shared__ __align__(16) unsigned short ads[16*200];  // ds A
  __shared__ float s_e0[16], s_e1[48];
  __shared__ int s_src[16], s_dst[16];
  const int tid  = threadIdx.x;
  const int lane = tid & 63, wave = tid >> 6;
  const int quad = lane >> 4, l15 = lane & 15;
  const int eb = blockIdx.x*16;

  // A0: indices, attr, escal
  if (tid < 16) { s_src[tid] = esrc[eb+tid]; s_dst[tid] = edst[eb+tid]; }
  if (tid >= 64 && tid < 128) {
    int t = tid-64, e = t>>2, q = t&3;
    float a = eattr[(eb+e)*4+q];
    if (q == 0) s_e0[e] = a; else s_e1[(q-1)*16+e] = a;
  }
  #pragma unroll
  for (int it = 0; it < 2; ++it) {
    int idx = tid + it*256;
    int e = idx>>5, i = idx&31;
    aes[e*40+i] = f2bf(escal[(eb+e)*32+i]);
  }
  __syncthreads();

  // A1: h = silu(escal@W1 + b1), one 16-col tile per wave
  {
    int col = wave*16 + l15;
    bshort8 a = *(const bshort8*)&aes[l15*40 + quad*8];
    bshort8 b = *(const bshort8*)&swz[O_W1 + (wave*64 + lane)*8];
    float bb = rad_b1[col];
    floatx4 acc = {bb,bb,bb,bb};
    acc = MFMA16(a, b, acc);
    #pragma unroll
    for (int r=0;r<4;r++) ah[(quad*4+r)*72 + col] = f2bf(siluf(acc[r]));
  }
  __syncthreads();

  // A2: needed w cols only — w1 (W2 tiles 0..7) and w4 (W2 tiles 20..23), 3 tiles/wave
  {
    bshort8 ha0 = *(const bshort8*)&ah[l15*72 + quad*8];
    bshort8 ha1 = *(const bshort8*)&ah[l15*72 + 32 + quad*8];
    #pragma unroll
    for (int t=0;t<3;t++) {
      int ti = wave*3 + t;                 // 0..11 local tile
      int nt = (ti < 8) ? ti : ti + 12;    // W2 tile index
      float o = rad_off[nt*16 + l15];
      floatx4 acc = {o,o,o,o};
      acc = MFMA16(ha0, *(const bshort8*)&swz[O_W2 + ((nt*2+0)*64+lane)*8], acc);
      acc = MFMA16(ha1, *(const bshort8*)&swz[O_W2 + ((nt*2+1)*64+lane)*8], acc);
      #pragma unroll
      for (int r=0;r<4;r++) sw[(quad*4+r)*192 + ti*16 + l15] = f2bf(acc[r]);
    }
  }
  __syncthreads();

  // B: dtp1 scalar rows -> ds A-matrix
  #pragma unroll
  for (int it = 0; it < 8; ++it) {
    int t = tid + it*256;
    int m = t&127, e = t>>7;
    float msgs = ms_s[s_src[e]*128+m] + md_s[s_dst[e]*128+m];
    ads[e*200+m] = f2bf(bf2f(sw[e*192+m])*msgs*s_e0[e]);          // os1
  }
  #pragma unroll
  for (int it = 0; it < 4; ++it) {
    int t = tid + it*256;
    int k = t&63, e = t>>6;
    const float* pa = &ms_v[s_src[e]*192 + k*3];
    const float* pb = &md_v[s_dst[e]*192 + k*3];
    float vx = pa[0]+pb[0], vy = pa[1]+pb[1], vz = pa[2]+pb[2];
    float d = vx*s_e1[0+e] + vy*s_e1[16+e] + vz*s_e1[32+e];
    ads[e*200+128+k] = f2bf(bf2f(sw[e*192+128+k])*d*INV_SQRT3f);  // os2
  }
  __syncthreads();

  // C: al = ds@Walpha + balpha ; sleaky*alpha_dot ; butterfly reduce 16 -> logits
  {
    bshort8 fa[6];
    #pragma unroll
    for (int kt=0;kt<6;kt++) fa[kt] = *(const bshort8*)&ads[l15*200 + kt*32 + quad*8];
    #pragma unroll
    for (int t=0;t<2;t++) {
      int h = wave*2 + t;                  // n-tile == head (AH0 == 16)
      int col = h*16 + l15;
      float bb = balpha[col];
      floatx4 acc = {bb,bb,bb,bb};
      #pragma unroll
      for (int kt=0;kt<6;kt++)
        acc = MFMA16(fa[kt], *(const bshort8*)&swz[O_WALP + ((h*6+kt)*64+lane)*8], acc);
      float ad = alpha_dot[col];
      #pragma unroll
      for (int r=0;r<4;r++) {
        float p = sleaky(acc[r])*ad;
        p += __shfl_xor(p, 1);
        p += __shfl_xor(p, 2);
        p += __shfl_xor(p, 4);
        p += __shfl_xor(p, 8);
        if (l15 == 0) {
          int row = quad*4 + r;
          logits[(eb+row)*8 + h] = p;
          atomicMaxF(&mx[s_dst[row]*8+h], p);
        }
      }
    }
  }
}

// ---------------------------------------------------------------- edge pass 2: MFMA value pipeline, 16 edges/block
__global__ __launch_bounds__(256) void e2_agg(
    const float* __restrict__ ms_s, const float* __restrict__ md_s,
    const float* __restrict__ ms_v, const float* __restrict__ md_v,
    const int* __restrict__ esrc, const int* __restrict__ edst,
    const float* __restrict__ eattr, const float* __restrict__ escal,
    const float* __restrict__ rad_b1, const float* __restrict__ rad_off,
    const float* __restrict__ bact, const float* __restrict__ w_int,
    const float* __restrict__ bval,
    const unsigned short* __restrict__ swz,
    const float* __restrict__ logits, const float* __restrict__ mx,
    float* __restrict__ den, float* __restrict__ num) {
  __shared__ __align__(16) char smem[65152];
  unsigned short* sw  = (unsigned short*)smem;            // 16x448 bf16 (A2->B)
  float* scalf = (float*)smem;                            // 16x192 (C->D)
  float* gshf  = (float*)(smem+12288);                    // 16x64  (C->D)
  float* gbf   = (float*)(smem+16384);                    // 3x16x64(C->D)
  float* soutf = (float*)smem;                            // 16x320 (E->end)
  float* vshf  = (float*)(smem+20480);                    // 16x64  (E->F)
  float* vbf   = (float*)(smem+24576);                    // 3x16x64(E->F)
  unsigned short* ads  = (unsigned short*)(smem+36864);   // 16x200 bf16 A (ds / vs)
  unsigned short* at1  = (unsigned short*)(smem+43264);   // 16x136 bf16 A (t1 / t2)
  unsigned short* advb = (unsigned short*)(smem+47616);   // 3x16x136 bf16 A (dvB / vvB)
  unsigned short* aes  = (unsigned short*)(smem+60672);   // 16x40 bf16 A (escal)
  unsigned short* ah   = (unsigned short*)(smem+61952);   // 16x72 bf16 A (silu h)
  float* s_e0 = (float*)(smem+64256);                     // 16
  float* s_e1 = (float*)(smem+64320);                     // 48 [c*16+e]
  float* s_ex = (float*)(smem+64512);                     // 128
  int* s_src  = (int*)(smem+65024);                       // 16
  int* s_dst  = (int*)(smem+65088);                       // 16
  const int tid  = threadIdx.x;
  const int lane = tid & 63, wave = tid >> 6;
  const int quad = lane >> 4, l15 = lane & 15;
  const int eb = blockIdx.x*16;

  // ---- A0
  if (tid < 16) { s_src[tid] = esrc[eb+tid]; s_dst[tid] = edst[eb+tid]; }
  if (tid >= 64 && tid < 128) {
    int t = tid-64, e = t>>2, q = t&3;
    float a = eattr[(eb+e)*4+q];
    if (q == 0) s_e0[e] = a; else s_e1[(q-1)*16+e] = a;
  }
  #pragma unroll
  for (int it = 0; it < 2; ++it) {
    int idx = tid + it*256;
    int e = idx>>5, i = idx&31;
    aes[e*40+i] = f2bf(escal[(eb+e)*32+i]);
  }
  __syncthreads();

  // ---- A1
  {
    int nt = wave, col = nt*16 + l15;
    bshort8 a = *(const bshort8*)&aes[l15*40 + quad*8];
    bshort8 b = *(const bshort8*)&swz[O_W1 + (nt*64 + lane)*8];
    float bb = rad_b1[col];
    floatx4 acc = {bb,bb,bb,bb};
    acc = MFMA16(a, b, acc);
    #pragma unroll
    for (int r=0;r<4;r++) ah[(quad*4+r)*72 + col] = f2bf(siluf(acc[r]));
  }
  __syncthreads();

  // ---- A2: full w (448 cols)
  {
    bshort8 ha0 = *(const bshort8*)&ah[l15*72 + quad*8];
    bshort8 ha1 = *(const bshort8*)&ah[l15*72 + 32 + quad*8];
    #pragma unroll
    for (int t=0;t<7;t++) {
      int nt = wave*7 + t, col = nt*16 + l15;
      float o = rad_off[col];
      floatx4 acc = {o,o,o,o};
      acc = MFMA16(ha0, *(const bshort8*)&swz[O_W2 + ((nt*2+0)*64+lane)*8], acc);
      acc = MFMA16(ha1, *(const bshort8*)&swz[O_W2 + ((nt*2+1)*64+lane)*8], acc);
      #pragma unroll
      for (int r=0;r<4;r++) sw[(quad*4+r)*448 + col] = f2bf(acc[r]);
    }
  }
  __syncthreads();

  // ---- B: dtp1 elementwise + gather
  #pragma unroll
  for (int it = 0; it < 8; ++it) {
    int t = tid + it*256;
    int m = t&127, e = t>>7;
    float msgs = ms_s[s_src[e]*128+m] + md_s[s_dst[e]*128+m];
    ads[e*200+m] = f2bf(bf2f(sw[e*448+m])*msgs*s_e0[e]);
    at1[e*136+m] = f2bf(bf2f(sw[e*448+128+m])*msgs);
  }
  #pragma unroll
  for (int it = 0; it < 4; ++it) {
    int t = tid + it*256;
    int k = t&63, e = t>>6;
    const float* pa = &ms_v[s_src[e]*192 + k*3];
    const float* pb = &md_v[s_dst[e]*192 + k*3];
    float vx = pa[0]+pb[0], vy = pa[1]+pb[1], vz = pa[2]+pb[2];
    float ex1 = s_e1[0+e], ey1 = s_e1[16+e], ez1 = s_e1[32+e];
    float d = vx*ex1 + vy*ey1 + vz*ez1;
    ads[e*200+128+k] = f2bf(bf2f(sw[e*448+320+k])*d*INV_SQRT3f);
    float w3v = bf2f(sw[e*448+256+k])*s_e0[e];
    float w5  = bf2f(sw[e*448+384+k])*INV_SQRT2f;
    advb[0*2176 + e*136 + k] = f2bf(w3v*vx);
    advb[1*2176 + e*136 + k] = f2bf(w3v*vy);
    advb[2*2176 + e*136 + k] = f2bf(w3v*vz);
    advb[0*2176 + e*136 + 64+k] = f2bf(w5*(vy*ez1 - vz*ey1));
    advb[1*2176 + e*136 + 64+k] = f2bf(w5*(vz*ex1 - vx*ez1));
    advb[2*2176 + e*136 + 64+k] = f2bf(w5*(vx*ey1 - vy*ex1));
  }
  __syncthreads();

  // ---- C
  {
    bshort8 fa[6];
    #pragma unroll
    for (int kt=0;kt<6;kt++) fa[kt] = *(const bshort8*)&ads[l15*200 + kt*32 + quad*8];
    #pragma unroll
    for (int t=0;t<3;t++) {
      int nt = wave + 4*t, col = nt*16 + l15;
      float bb = bact[col];
      floatx4 acc = {bb,bb,bb,bb};
      #pragma unroll
      for (int kt=0;kt<6;kt++)
        acc = MFMA16(fa[kt], *(const bshort8*)&swz[O_WAS + ((nt*6+kt)*64+lane)*8], acc);
      #pragma unroll
      for (int r=0;r<4;r++) scalf[(quad*4+r)*192 + col] = acc[r];
    }
    bshort8 ft[4];
    #pragma unroll
    for (int kt=0;kt<4;kt++) ft[kt] = *(const bshort8*)&at1[l15*136 + kt*32 + quad*8];
    {
      int nt = wave, col = nt*16 + l15;
      floatx4 acc = {0.f,0.f,0.f,0.f};
      #pragma unroll
      for (int kt=0;kt<4;kt++)
        acc = MFMA16(ft[kt], *(const bshort8*)&swz[O_WAVT + ((nt*4+kt)*64+lane)*8], acc);
      #pragma unroll
      for (int r=0;r<4;r++) gshf[(quad*4+r)*64 + col] = acc[r];
    }
    #pragma unroll
    for (int c=0;c<3;c++) {
      int nt = wave, col = nt*16 + l15;
      floatx4 acc = {0.f,0.f,0.f,0.f};
      #pragma unroll
      for (int kt=0;kt<4;kt++) {
        bshort8 fb = *(const bshort8*)&advb[c*2176 + l15*136 + kt*32 + quad*8];
        acc = MFMA16(fb, *(const bshort8*)&swz[O_WAVB + ((nt*4+kt)*64+lane)*8], acc);
      }
      #pragma unroll
      for (int r=0;r<4;r++) gbf[c*1024 + (quad*4+r)*64 + col] = acc[r];
    }
  }
  __syncthreads();

  // ---- D
  #pragma unroll
  for (int it = 0; it < 8; ++it) {
    int t = tid + it*256;
    int m = t&127, e = t>>7;
    float v = siluf(scalf[e*192+m]);
    ads[e*200+m] = f2bf(w_int[m]*v*s_e0[e]);
    at1[e*136+m] = f2bf(w_int[128+m]*v);
  }
  #pragma unroll
  for (int it = 0; it < 4; ++it) {
    int t = tid + it*256;
    int k = t&63, e = t>>6;
    float sg = sigm(scalf[e*192+128+k]);
    float gs = gshf[e*64+k];
    float ex1 = s_e1[0+e], ey1 = s_e1[16+e], ez1 = s_e1[32+e];
    float v0 = (gs*ex1 + gbf[0*1024 + e*64+k])*sg;
    float v1 = (gs*ey1 + gbf[1*1024 + e*64+k])*sg;
    float v2 = (gs*ez1 + gbf[2*1024 + e*64+k])*sg;
    float d = v0*ex1 + v1*ey1 + v2*ez1;
    ads[e*200+128+k] = f2bf(w_int[320+k]*d*INV_SQRT3f);
    float w3v = w_int[256+k]*s_e0[e];
    float w5  = w_int[384+k]*INV_SQRT2f;
    advb[0*2176 + e*136 + k] = f2bf(w3v*v0);
    advb[1*2176 + e*136 + k] = f2bf(w3v*v1);
    advb[2*2176 + e*136 + k] = f2bf(w3v*v2);
    advb[0*2176 + e*136 + 64+k] = f2bf(w5*(v1*ez1 - v2*ey1));
    advb[1*2176 + e*136 + 64+k] = f2bf(w5*(v2*ex1 - v0*ez1));
    advb[2*2176 + e*136 + 64+k] = f2bf(w5*(v0*ey1 - v1*ex1));
  }
  __syncthreads();

  // ---- E
  {
    bshort8 fa[6];
    #pragma unroll
    for (int kt=0;kt<6;kt++) fa[kt] = *(const bshort8*)&ads[l15*200 + kt*32 + quad*8];
    #pragma unroll
    for (int t=0;t<2;t++) {
      int nt = wave + 4*t, col = nt*16 + l15;
      float bb = bval[col];
      floatx4 acc = {bb,bb,bb,bb};
      #pragma unroll
      for (int kt=0;kt<6;kt++)
        acc = MFMA16(fa[kt], *(const bshort8*)&swz[O_WVS + ((nt*6+kt)*64+lane)*8], acc);
      #pragma unroll
      for (int r=0;r<4;r++) soutf[(quad*4+r)*320 + nt*40 + l15] = acc[r];
    }
    bshort8 ft[4];
    #pragma unroll
    for (int kt=0;kt<4;kt++) ft[kt] = *(const bshort8*)&at1[l15*136 + kt*32 + quad*8];
    {
      int nt = wave, col = nt*16 + l15;
      floatx4 acc = {0.f,0.f,0.f,0.f};
      #pragma unroll
      for (int kt=0;kt<4;kt++)
        acc = MFMA16(ft[kt], *(const bshort8*)&swz[O_WVVT + ((nt*4+kt)*64+lane)*8], acc);
      #pragma unroll
      for (int r=0;r<4;r++) vshf[(quad*4+r)*64 + col] = acc[r];
    }
    #pragma unroll
    for (int c=0;c<3;c++) {
      int nt = wave, col = nt*16 + l15;
      floatx4 acc = {0.f,0.f,0.f,0.f};
      #pragma unroll
      for (int kt=0;kt<4;kt++) {
        bshort8 fb = *(const bshort8*)&advb[c*2176 + l15*136 + kt*32 + quad*8];
        acc = MFMA16(fb, *(const bshort8*)&swz[O_WVVB + ((nt*4+kt)*64+lane)*8], acc);
      }
      #pragma unroll
      for (int r=0;r<4;r++) vbf[c*1024 + (quad*4+r)*64 + col] = acc[r];
    }
  }
  __syncthreads();

  // ---- F
  #pragma unroll
  for (int it = 0; it < 4; ++it) {
    int t = tid + it*256;
    int k = t&63, e = t>>6;
    float vs_ = vshf[e*64+k];
    int base = e*320 + (k>>3)*40 + 16 + (k&7)*3;
    #pragma unroll
    for (int c=0;c<3;c++)
      soutf[base + c] = vbf[c*1024 + e*64 + k] + s_e1[c*16+e]*vs_;
  }
  if (tid < 128) {
    int e = tid>>3, h = tid&7;
    float lg = logits[(eb+e)*8+h];
    float m  = mx[s_dst[e]*8+h];
    float ex = __expf(lg - m);
    s_ex[e*8+h] = ex;
    atomicAdd(&den[s_dst[e]*8+h], ex);
  }
  __syncthreads();

  for (int idx = tid; idx < 5120; idx += 256) {
    int e = idx/320, j = idx - e*320;
    int h = j/40;
    atomicAdd(&num[s_dst[e]*320 + j], soutf[e*320+j]*s_ex[e*8+h]);
  }
}

// ---------------------------------------------------------------- node post (unchanged)
__global__ __launch_bounds__(256) void node_post(
    const float* __restrict__ num, const float* __restrict__ den,
    const float* __restrict__ Wproj_s, const float* __restrict__ bproj,
    const float* __restrict__ Wproj_v, float* __restrict__ out) {
  __shared__ __align__(16) float s_ns[128*8];
  __shared__ __align__(16) float s_nv[192*8];
  const int tid = threadIdx.x;
  const int n0 = blockIdx.x*8;
  for (int idx = tid; idx < 8*320; idx += 256) {
    int n = idx/320, j = idx - n*320;
    int h = j/40, r = j - h*40;
    float a = num[(n0+n)*320+j] / (den[(n0+n)*8+h] + 1e-16f);
    if (r < 16) s_ns[(h*16+r)*8+n] = a;
    else        s_nv[(h*24 + (r-16))*8+n] = a;
  }
  __syncthreads();
  {
    int g = tid>>7, j = tid&127;
    float acc[4]; float b = bproj[j];
    #pragma unroll
    for (int i=0;i<4;i++) acc[i]=b;
    for (int k=0;k<128;k++) {
      float wv = Wproj_s[k*128+j];
      float4 s4 = *(const float4*)&s_ns[k*8+g*4];
      acc[0]+=s4.x*wv; acc[1]+=s4.y*wv; acc[2]+=s4.z*wv; acc[3]+=s4.w*wv;
    }
    #pragma unroll
    for (int i=0;i<4;i++) out[(n0+g*4+i)*320 + j] = acc[i];
  }
  if (tid < 192) {
    int c = tid>>6, k = tid&63;
    float acc[8];
    #pragma unroll
    for (int e=0;e<8;e++) acc[e]=0.f;
    for (int m=0;m<64;m++) {
      float wv = Wproj_v[m*64+k];
      float4 v0 = *(const float4*)&s_nv[(m*3+c)*8];
      float4 v1 = *(const float4*)&s_nv[(m*3+c)*8+4];
      acc[0]+=v0.x*wv; acc[1]+=v0.y*wv; acc[2]+=v0.z*wv; acc[3]+=v0.w*wv;
      acc[4]+=v1.x*wv; acc[5]+=v1.y*wv; acc[6]+=v1.z*wv; acc[7]+=v1.w*wv;
    }
    #pragma unroll
    for (int e=0;e<8;e++) out[(n0+e)*320 + 128 + k*3 + c] = acc[e];
  }
}

// ---------------------------------------------------------------- launch
extern "C" void kernel_launch(void* const* d_in, const int* in_sizes, int n_in,
                              void* d_out, int out_size, void* d_ws, size_t ws_size,
                              hipStream_t stream) {
  (void)in_sizes; (void)n_in; (void)out_size; (void)ws_size;
  const float* node_input = (const float*)d_in[0];
  const int*   esrc       = (const int*)d_in[1];
  const int*   edst       = (const int*)d_in[2];
  const float* eattr      = (const float*)d_in[3];
  const float* escal      = (const float*)d_in[4];
  const float* Wsrc_s     = (const float*)d_in[5];
  const float* Wsrc_v     = (const float*)d_in[6];
  const float* bsrc       = (const float*)d_in[7];
  const float* Wdst_s     = (const float*)d_in[8];
  const float* Wdst_v     = (const float*)d_in[9];
  const float* rad_W1     = (const float*)d_in[10];
  const float* rad_b1     = (const float*)d_in[11];
  const float* rad_W2     = (const float*)d_in[12];
  const float* rad_off    = (const float*)d_in[13];
  const float* Wact_s     = (const float*)d_in[14];
  const float* bact       = (const float*)d_in[15];
  const float* Wact_v     = (const float*)d_in[16];
  const float* Walpha     = (const float*)d_in[17];
  const float* balpha     = (const float*)d_in[18];
  const float* w_int      = (const float*)d_in[19];
  const float* Wval_s     = (const float*)d_in[20];
  const float* bval       = (const float*)d_in[21];
  const float* Wval_v     = (const float*)d_in[22];
  const float* alpha_dot  = (const float*)d_in[23];
  const float* Wproj_s    = (const float*)d_in[24];
  const float* bproj      = (const float*)d_in[25];
  const float* Wproj_v    = (const float*)d_in[26];
  float* out = (float*)d_out;

  float* ws = (float*)d_ws;
  float* ms_s   = ws;                 // N*128
  float* md_s   = ws + 1280000;       // N*128
  float* ms_v   = ws + 2560000;       // N*192
  float* md_v   = ws + 4480000;       // N*192
  float* logits = ws + 6400000;       // E*8
  float* mx     = ws + 7680000;       // N*8
  float* den    = ws + 7760000;       // N*8
  float* num    = ws + 7840000;       // N*320  -> ends 11,040,000 floats
  unsigned short* swz = (unsigned short*)(ws + 11040000);  // 149,504 ushorts

  k_prep<<<584, 256, 0, stream>>>(rad_W1, rad_W2, Wact_s, Wact_v, Wval_s, Wval_v, Walpha, swz);
  k_init<<<12500, 256, 0, stream>>>(num, den, (int*)mx);
  node_pre<<<1250, 256, 0, stream>>>(node_input, Wsrc_s, Wsrc_v, bsrc, Wdst_s, Wdst_v,
                                     ms_s, md_s, ms_v, md_v);
  e1_logits<<<10000, 256, 0, stream>>>(ms_s, md_s, ms_v, md_v, esrc, edst, eattr, escal,
                                       rad_b1, rad_off, balpha, alpha_dot,
                                       swz, logits, mx);
  e2_agg<<<10000, 256, 0, stream>>>(ms_s, md_s, ms_v, md_v, esrc, edst, eattr, escal,
                                    rad_b1, rad_off, bact, w_int, bval,
                                    swz, logits, mx, den, num);
  node_post<<<1250, 256, 0, stream>>>(num, den, Wproj_s, bproj, Wproj_v, out);
}